// Round 13
// baseline (2297.751 us; speedup 1.0000x reference)
//
#include <hip/hip_runtime.h>
#include <hip/hip_bf16.h>
#include <math.h>

typedef __hip_bfloat16 bf16;
typedef __attribute__((ext_vector_type(8))) short bf16x8;
typedef __attribute__((ext_vector_type(4))) float f32x4;

#define NN 16
#define CCH 256
#define HH 56
#define WW 56
#define SSP 3136
#define GG 8
#define GPH 16
#define GPF 32
#define OCT 512
#define RL 111
#define EPSV 1e-5f
#define CNT_PROJ 50176.0f
#define CNT_SIM  2809856.0f

__device__ __forceinline__ float bf2f(bf16 v){ return __bfloat162float(v); }
__device__ __forceinline__ bf16 f2bf(float v){ return __float2bfloat16(v); }
__device__ __forceinline__ short f2s(float f){ bf16 h = __float2bfloat16(f); return __builtin_bit_cast(short, h); }
__device__ __forceinline__ float s2f(short s){ bf16 h = __builtin_bit_cast(bf16, s); return __bfloat162float(h); }
__device__ __forceinline__ unsigned pk2(float a, float b){
  return (unsigned)(unsigned short)f2s(a) | ((unsigned)(unsigned short)f2s(b)<<16);
}
__device__ __forceinline__ float aload(float* p){ return atomicAdd(p, 0.0f); }  // forced L2 read

__device__ __forceinline__ void gl16(const void* g, void* l){
  __builtin_amdgcn_global_load_lds((const __attribute__((address_space(1))) void*)g,
                                   (__attribute__((address_space(3))) void*)l, 16, 0, 0);
}

// ---- f32 workspace region layout (float indices) ----
#define F_PR 0
#define F_PD 4096
#define F_SR 8192
#define F_SD 12288
#define F_PSUM 16384
#define F_PSQ  16896
#define F_PA   17408
#define F_PB   17920
#define F_SSUM 18432
#define F_SSQ  18464
#define F_SA   18496
#define F_SB   18528
#define F_OSUM 18560
#define F_OSQ  19072
#define F_OA   19584
#define F_OB   20096
#define F_CNT_G 20608
#define F_CNT_S 20609
#define F_CNT_A 20610
#define F_ACC_END 20612
#define F_TOT  20612
// bf16 table region (shorts)
#define T_RQ 0        // [112][24]
#define T_RK 2688     // [112][24]
#define T_RV 5376     // [32][128]
#define T_TOT 9472

// k_att LDS layout (bytes)
#define STQ 24
#define SQT 58
#define STA 72
#define STSH 136
#define STG 72
#define OFF_QA   0
#define OFF_KA   3072
#define OFF_QR   6144
#define OFF_KR   19136
#define OFF_VB   32128
#define OFF_FAC  36736
#define OFF_OST  36992
#define SMSZ     37504
#define OFF_SIMA 0
#define OFF_SIMSH 9216
#define ZERO_I4  1664

// k_simstat LDS (shorts per buffer)
#define SB_QA 0
#define SB_KA 1536
#define SB_QG 3072
#define SB_KG 4224
#define SB_TOT 5376
#define SB_ZI4 1344

// ============ K1: prep (+ tables in block (0,0)) ============
__global__ __launch_bounds__(256) void k_prep(const float* __restrict__ x, const float* __restrict__ xd,
                                              const float* __restrict__ rel,
                                              float* __restrict__ fws, short* __restrict__ tb,
                                              bf16* __restrict__ xT, bf16* __restrict__ xdT, bf16* __restrict__ xfT){
  __shared__ __align__(16) short tx[32*264];
  __shared__ __align__(16) short td[32*264];
  __shared__ __align__(16) short tf[32*264];
  int s0 = blockIdx.x*32, n = blockIdx.y;
  int t = threadIdx.x;
  int si = t & 31, cg = t >> 5;
  for(int cc=0; cc<CCH; cc+=8){
    int c = cc + cg;
    size_t gi = ((size_t)n*CCH + c)*SSP + s0 + si;
    float vx = x[gi], vd = xd[gi];
    tx[si*264+c] = f2s(vx);
    td[si*264+c] = f2s(vd);
    tf[si*264+c] = f2s(vx*vd);
  }
  __syncthreads();
  {
    float s1=0.f, s2=0.f;
    for(int sr=0; sr<32; sr++){ s1 += s2f(tx[sr*264+t]); s2 += s2f(td[sr*264+t]); }
    atomicAdd(&fws[F_PR+n*CCH+t], s1);
    atomicAdd(&fws[F_PD+n*CCH+t], s2);
  }
  size_t rbase = (size_t)n*SSP;
  for(int idx=t; idx<32*32; idx+=256){
    int sr2 = idx>>5, ch = idx&31;
    int sp = s0 + sr2;
    int s2 = (sp%WW)*HH + sp/WW;
    float4 v1 = *(const float4*)(tx + sr2*264 + ch*8);
    float4 v2 = *(const float4*)(td + sr2*264 + ch*8);
    float4 v3 = *(const float4*)(tf + sr2*264 + ch*8);
    *reinterpret_cast<float4*>(xT  + (rbase + s2)*CCH + ch*8) = v1;
    *reinterpret_cast<float4*>(xdT + (rbase + s2)*CCH + ch*8) = v2;
    *reinterpret_cast<float4*>(xfT + (rbase + s2)*CCH + ch*8) = v3;
  }
  // fold-in: embedding tables (independent; consumed two kernels later)
  if(blockIdx.x==0 && blockIdx.y==0){
    for(int idx=t; idx<112*24; idx+=256){
      int d = idx/24, c = idx - d*24;
      short vq=0, vk=0;
      if(c<16 && d<RL){ vq = f2s(rel[c*RL+d]); vk = f2s(rel[(16+c)*RL+d]); }
      tb[T_RQ+idx]=vq; tb[T_RK+idx]=vk;
    }
    for(int idx=t; idx<32*128; idx+=256){
      int c = idx>>7, d = idx&127;
      short v=0;
      if(d<RL) v = f2s(rel[(32+c)*RL+d]);
      tb[T_RV+idx]=v;
    }
  }
}

// ============ K2: channel attention scales ============
__global__ __launch_bounds__(256) void k_chanatt(const float* __restrict__ wr, const float* __restrict__ br,
                                                 const float* __restrict__ wd, const float* __restrict__ bd,
                                                 float* __restrict__ fws){
  int c = threadIdx.x, n = blockIdx.x;
  __shared__ float red[256];
  __shared__ float prl[256], pdl[256];
  prl[c]=fws[F_PR+n*CCH+c]*(1.f/SSP); pdl[c]=fws[F_PD+n*CCH+c]*(1.f/SSP);
  __syncthreads();
  float dr=br[c], dd=bd[c];
  for(int k=0;k<CCH;k++){ dr = fmaf(prl[k], wr[c*CCH+k], dr); dd = fmaf(pdl[k], wd[c*CCH+k], dd); }
  dr = fmaxf(dr,0.f); dd = fmaxf(dd,0.f);
  float car = 1.f/(1.f+expf(-dr));
  float cad = 1.f/(1.f+expf(-dd));
  float tv = car+cad;
  red[c]=tv; __syncthreads();
  for(int st=128;st>0;st>>=1){ if(c<st) red[c]=fmaxf(red[c],red[c+st]); __syncthreads(); }
  float mx = red[0]; __syncthreads();
  float e = expf(tv-mx);
  red[c]=e; __syncthreads();
  for(int st=128;st>0;st>>=1){ if(c<st) red[c]+=red[c+st]; __syncthreads(); }
  float co = e/red[0];
  fws[F_SR+n*CCH+c] = co+car;
  fws[F_SD+n*CCH+c] = co+cad;
}

// ============ K3: weight prep ============
__global__ __launch_bounds__(256) void k_wprep(const float* __restrict__ qw, const float* __restrict__ kw,
                                               const float* __restrict__ vw, const float* __restrict__ fws,
                                               bf16* __restrict__ wqs, bf16* __restrict__ wks, bf16* __restrict__ vwb){
  int b = blockIdx.x, t = threadIdx.x;
  if(b<16){
    const float* sr = fws + F_SR + b*CCH;
    const float* sd = fws + F_SD + b*CCH;
    for(int idx=t; idx<128*256; idx+=256){
      int c = idx & 255;
      wqs[b*32768+idx] = f2bf(qw[idx]*sr[c]);
      wks[b*32768+idx] = f2bf(kw[idx]*sd[c]);
    }
  } else {
    for(int idx=t; idx<256*256; idx+=256) vwb[idx] = f2bf(vw[idx]);
  }
}

// ============ K4: MFMA projection GEMM — 64s x 128o tiles (A staged once per o-pair) ============
__global__ __launch_bounds__(256) void k_gemm(const bf16* __restrict__ xT, const bf16* __restrict__ xdT,
                                              const bf16* __restrict__ xfT,
                                              const bf16* __restrict__ wqs, const bf16* __restrict__ wks,
                                              const bf16* __restrict__ vwb,
                                              const float* __restrict__ qg, const float* __restrict__ qb,
                                              const float* __restrict__ kg, const float* __restrict__ kb,
                                              const float* __restrict__ vg, const float* __restrict__ vb,
                                              float* __restrict__ fws, bf16* __restrict__ proj){
  __shared__ __align__(16) char sm[50176];   // A0 8K | A1 8K | B0 16K | B1 16K | sst 1K
  __shared__ unsigned lastG;
  int bid = blockIdx.x;
  int sw = (bid & 7)*392 + (bid >> 3);       // 3136 = 8*392
  int p = sw & 3;
  int rest = sw >> 2;
  int s_t = rest % 49;
  int n   = rest / 49;
  int s0g = s_t*64;

  const bf16* Ag = (p==0 ? xT : (p==1 ? xdT : xfT)) + (size_t)n*SSP*CCH;
  const bf16* Wg = (p==0) ? (wqs + (size_t)n*32768)
                 : (p==1) ? (wks + (size_t)n*32768)
                          : (vwb + (size_t)(p-2)*128*256);

  int tid = threadIdx.x;
  int w = tid>>6, lane = tid&63;
  int l15 = lane & 15, l4 = lane >> 4;

  float* sst = (float*)(sm + 49152);
  sst[tid]=0.f;

  f32x4 acc[2][4];
  #pragma unroll
  for(int f=0;f<2;f++)
    #pragma unroll
    for(int e=0;e<4;e++) acc[f][e]=(f32x4){0,0,0,0};

  auto stage = [&](int b, int kk){
    #pragma unroll
    for(int j=0;j<2;j++){
      int rowstart = w*16 + j*8;
      int row = rowstart + (lane>>3);
      int ch  = (lane&7) ^ (row&7);
      gl16(Ag + (size_t)(s0g + row)*CCH + kk*64 + ch*8, sm + (b?8192:0) + rowstart*128);
    }
    #pragma unroll
    for(int j=0;j<4;j++){
      int rowstart = w*32 + j*8;
      int row = rowstart + (lane>>3);
      int ch  = (lane&7) ^ (row&7);
      gl16(Wg + (size_t)row*CCH + kk*64 + ch*8, sm + 16384 + (b?16384:0) + rowstart*128);
    }
  };

  stage(0,0);
  __syncthreads();
  int cur=0;
  int sl0 = (w&1)*32, ol0 = (w>>1)*64;
  for(int kk=0;kk<4;kk++){
    if(kk<3) stage(cur^1, kk+1);
    const short* Ab = (const short*)(sm + (cur?8192:0));
    const short* Bb = (const short*)(sm + 16384 + (cur?16384:0));
    #pragma unroll
    for(int kh=0;kh<2;kh++){
      bf16x8 a[2], b[4];
      #pragma unroll
      for(int f=0;f<2;f++){
        int sr = sl0 + f*16 + l15;
        int chv = (kh*4 + l4) ^ (sr&7);
        a[f] = *(const bf16x8*)(Ab + sr*64 + chv*8);
      }
      #pragma unroll
      for(int e=0;e<4;e++){
        int orw = ol0 + e*16 + l15;
        int chv = (kh*4 + l4) ^ (orw&7);
        b[e] = *(const bf16x8*)(Bb + orw*64 + chv*8);
      }
      #pragma unroll
      for(int f=0;f<2;f++)
        #pragma unroll
        for(int e=0;e<4;e++)
          acc[f][e] = __builtin_amdgcn_mfma_f32_16x16x32_bf16(a[f], b[e], acc[f][e], 0,0,0);
    }
    __syncthreads();
    cur ^= 1;
  }

  #pragma unroll
  for(int e=0;e<4;e++){
    float s1=0.f, s2=0.f;
    #pragma unroll
    for(int f=0;f<2;f++)
      #pragma unroll
      for(int r=0;r<4;r++){ float v=acc[f][e][r]; s1+=v; s2+=v*v; }
    s1 += __shfl_xor(s1,16); s2 += __shfl_xor(s2,16);
    s1 += __shfl_xor(s1,32); s2 += __shfl_xor(s2,32);
    if(l4==0){
      int ol = ol0 + e*16 + l15;
      atomicAdd(&sst[ol], s1);
      atomicAdd(&sst[128+ol], s2);
    }
  }
  #pragma unroll
  for(int f=0;f<2;f++)
    #pragma unroll
    for(int e=0;e<4;e++){
      int sbase = s0g + (w&1)*32 + f*16 + l4*4;
      int o = p*128 + ol0 + e*16 + l15;
      short4 pk;
      pk.x = f2s(acc[f][e][0]); pk.y = f2s(acc[f][e][1]);
      pk.z = f2s(acc[f][e][2]); pk.w = f2s(acc[f][e][3]);
      *reinterpret_cast<short4*>(proj + ((size_t)n*OCT + o)*SSP + sbase) = pk;
    }
  __syncthreads();
  if(tid<128){
    int og = p*128 + tid;
    atomicAdd(&fws[F_PSUM+og], sst[tid]);
    atomicAdd(&fws[F_PSQ+og],  sst[128+tid]);
  }
  // last-block finalize (proj BN a,b)
  __threadfence();
  if(tid==0) lastG = atomicAdd((unsigned*)&fws[F_CNT_G], 1u);
  __syncthreads();
  if(lastG == 3135u){
    for(int o=tid; o<512; o+=256){
      float ps = aload(&fws[F_PSUM+o]);
      float pq = aload(&fws[F_PSQ+o]);
      float m = ps*(1.0f/CNT_PROJ);
      float var = pq*(1.0f/CNT_PROJ) - m*m;
      float g,b;
      if(o<128){ g=qg[o]; b=qb[o]; }
      else if(o<256){ g=kg[o-128]; b=kb[o-128]; }
      else { g=vg[o-256]; b=vb[o-256]; }
      float a = g*rsqrtf(var+EPSV);
      fws[F_PA+o]=a; fws[F_PB+o]=b-m*a;
    }
  }
}

// ============ K5: sim-BN stats — 7 w per block, double-buffered (+ last-block finalize) ============
__global__ __launch_bounds__(256) void k_simstat(const bf16* __restrict__ proj,
                                                 const short* __restrict__ tb,
                                                 const float* __restrict__ sg, const float* __restrict__ sb,
                                                 float* __restrict__ fws){
  __shared__ __align__(16) short smS[2*SB_TOT];
  __shared__ float redW[4][4];
  __shared__ float red2[2];
  __shared__ unsigned lastS;
  int wq = blockIdx.x, n = blockIdx.y, g = blockIdx.z;
  int t = threadIdx.x;
  int W = t>>6, lane = t&63;
  int l15 = lane&15, l4 = lane>>4;
  const short* rqB = tb + T_RQ;
  const short* rkB = tb + T_RK;
  const bf16x8 z8 = {};

  for(int i=t; i<SB_ZI4; i+=256) ((int4*)smS)[i] = (int4){0,0,0,0};

  int isLoader = (t<224);
  int rid = t/7, ch = t - rid*7;
  int isK = rid>=16, c = rid&15;
  int o = (isK?128:0) + g*GPH + c;
  float pa=0.f, pb=0.f;
  const bf16* gsrc = proj + ((size_t)n*OCT+o)*SSP + ch*8;
  if(isLoader){ pa = fws[F_PA+o]; pb = fws[F_PB+o]; }
  int w0 = wq*7;

  auto stageWrite = [&](short* buf, bf16x8 vv){
    bf16x8 rv;
    #pragma unroll
    for(int e=0;e<8;e++) rv[e] = f2s(pa*s2f(vv[e])+pb);
    short* dA = buf + (isK? SB_KA : SB_QA);
    #pragma unroll
    for(int e=0;e<8;e++) dA[(ch*8+e)*STQ + c] = rv[e];
    short* gRow = buf + (isK? SB_KG : SB_QG) + c*STG;
    *(bf16x8*)(gRow + ch*8) = rv;
  };

  bf16x8 ld = z8;
  if(isLoader) ld = *(const bf16x8*)(gsrc + (size_t)w0*HH);
  __syncthreads();
  if(isLoader) stageWrite(smS, ld);
  __syncthreads();

  float sQ=0.f,qQ=0.f,sK=0.f,qK=0.f,pSS=0.f,pS=0.f;
  #pragma unroll 1
  for(int it=0; it<7; it++){
    bf16x8 nx = z8;
    if(it<6 && isLoader) nx = *(const bf16x8*)(gsrc + (size_t)(w0+it+1)*HH);
    const short* buf = smS + (it&1)*SB_TOT;
    const short* qA = buf + SB_QA;
    const short* kA = buf + SB_KA;
    const short* qG = buf + SB_QG;
    const short* kG = buf + SB_KG;

    for(int T=W; T<56; T+=4){
      int tk = (T>=28);
      int t2 = tk ? T-28 : T;
      int ti = t2/7, td = t2-7*ti;
      int i0 = ti*16, d0 = td*16;
      const short* aBase = tk ? kA : qA;
      const short* bBase = tk ? rkB : rqB;
      bf16x8 av = (l4<2)? *(const bf16x8*)(aBase + (i0+l15)*STQ + l4*8) : z8;
      bf16x8 bv = (l4<2)? *(const bf16x8*)(bBase + (d0+l15)*24 + l4*8) : z8;
      f32x4 acc = {0.f,0.f,0.f,0.f};
      acc = __builtin_amdgcn_mfma_f32_16x16x32_bf16(av, bv, acc, 0,0,0);
      int d = d0 + l15;
      #pragma unroll
      for(int r=0;r<4;r++){
        int i = i0 + l4*4 + r;
        int dmi = d - i;
        if(dmi>=0 && dmi<56){
          float v = acc[r];
          if(tk){ sK += v; qK += v*v; }
          else  { sQ += v; qQ += v*v; }
        }
      }
    }
    if(W==0){
      bf16x8 a0 = *(const bf16x8*)(qG + l15*STG + l4*8);
      bf16x8 a1 = *(const bf16x8*)(qG + l15*STG + 32 + l4*8);
      f32x4 gq = {0.f,0.f,0.f,0.f};
      gq = __builtin_amdgcn_mfma_f32_16x16x32_bf16(a0, a0, gq, 0,0,0);
      gq = __builtin_amdgcn_mfma_f32_16x16x32_bf16(a1, a1, gq, 0,0,0);
      bf16x8 b0 = *(const bf16x8*)(kG + l15*STG + l4*8);
      bf16x8 b1 = *(const bf16x8*)(kG + l15*STG + 32 + l4*8);
      f32x4 gk = {0.f,0.f,0.f,0.f};
      gk = __builtin_amdgcn_mfma_f32_16x16x32_bf16(b0, b0, gk, 0,0,0);
      gk = __builtin_amdgcn_mfma_f32_16x16x32_bf16(b1, b1, gk, 0,0,0);
      pSS += gq[0]*gk[0]+gq[1]*gk[1]+gq[2]*gk[2]+gq[3]*gk[3];
    } else if(W==1){
      float rsum = 0.f;
      if(lane<32){
        const short* row = (lane<16)? (qG + lane*STG) : (kG + (lane-16)*STG);
        #pragma unroll
        for(int i8=0;i8<7;i8++){
          bf16x8 v8 = *(const bf16x8*)(row + i8*8);
          #pragma unroll
          for(int e=0;e<8;e++) rsum += s2f(v8[e]);
        }
      }
      float kv = __shfl(rsum, (lane+16)&63);
      if(lane<16) pS += rsum*kv;
    }

    if(it<6){
      __syncthreads();
      if(isLoader) stageWrite(smS + ((it+1)&1)*SB_TOT, nx);
      __syncthreads();
    }
  }

  float b4[4] = {sQ,qQ,sK,qK};
  #pragma unroll
  for(int u=0;u<4;u++){
    float v = b4[u];
    #pragma unroll
    for(int msk=1;msk<64;msk<<=1) v += __shfl_xor(v,msk);
    if(lane==0) redW[W][u] = v;
  }
  if(W==0){
    float p = pSS;
    #pragma unroll
    for(int msk=1;msk<64;msk<<=1) p += __shfl_xor(p,msk);
    if(lane==0) red2[1] = p;
  } else if(W==1){
    float p = (lane<16)? pS : 0.f;
    #pragma unroll
    for(int msk=1;msk<16;msk<<=1) p += __shfl_xor(p,msk);
    if(lane==0) red2[0] = p;
  }
  __syncthreads();
  if(t<4){
    float s = redW[0][t]+redW[1][t]+redW[2][t]+redW[3][t];
    int tgt = (t==0)? (F_SSUM+8+g) : (t==1)? (F_SSQ+8+g) : (t==2)? (F_SSUM+16+g) : (F_SSQ+16+g);
    atomicAdd(&fws[tgt], s);
  } else if(t==4){
    atomicAdd(&fws[F_SSUM+g], red2[0]);
  } else if(t==5){
    atomicAdd(&fws[F_SSQ+g], red2[1]);
  }
  // last-block finalize (sim BN a,b)
  __threadfence();
  if(t==0) lastS = atomicAdd((unsigned*)&fws[F_CNT_S], 1u);
  __syncthreads();
  if(lastS == 1023u && t<24){
    float s = aload(&fws[F_SSUM+t]);
    float q = aload(&fws[F_SSQ+t]);
    float m = s*(1.0f/CNT_SIM);
    float var = q*(1.0f/CNT_SIM) - m*m;
    float a = sg[t]*rsqrtf(var+EPSV);
    fws[F_SA+t]=a; fws[F_SB+t]=sb[t]-m*a;
  }
}

// ============ K6: main MFMA attention (+ last-block out-BN finalize) ============
__global__ __launch_bounds__(512) void k_att(const bf16* __restrict__ proj,
                                             const short* __restrict__ tb,
                                             const float* __restrict__ og, const float* __restrict__ ob,
                                             float* __restrict__ fws,
                                             bf16* __restrict__ svw, bf16* __restrict__ svew){
  __shared__ __align__(16) char sm[SMSZ];
  __shared__ unsigned lastA;
  int g = blockIdx.x, w = blockIdx.y, n = blockIdx.z;
  int tid = threadIdx.x;
  int W = tid >> 6, lane = tid & 63;
  int l15 = lane & 15, l4 = lane >> 4;
  short* qA = (short*)(sm + OFF_QA);
  short* kA = (short*)(sm + OFF_KA);
  short* qrT = (short*)(sm + OFF_QR);
  short* krT = (short*)(sm + OFF_KR);
  short* vB  = (short*)(sm + OFF_VB);
  float* rfacL = (float*)(sm + OFF_FAC);
  const short* rqB = tb + T_RQ;
  const short* rkB = tb + T_RK;
  const short* rvBg = tb + T_RV;
  const float* PA = fws + F_PA;
  const float* PB = fws + F_PB;
  const bf16x8 z8 = {};

  float aqk = fws[F_SA+g], aqr = fws[F_SA+8+g], akr = fws[F_SA+16+g];
  float bsum = fws[F_SB+g]+fws[F_SB+8+g]+fws[F_SB+16+g];

  if(tid<128) ((float*)(sm+OFF_OST))[tid]=0.f;
  if(tid<448){
    int rid = tid/7, ch = tid - rid*7;
    int o, c, isV=0;
    if(rid<16){ c=rid; o = g*GPH + c; }
    else if(rid<32){ c=rid-16; o = 128 + g*GPH + c; }
    else { c=rid-32; o = 256 + g*GPF + c; isV=1; }
    float pa = PA[o], pb = PB[o];
    const bf16* src = proj + ((size_t)n*OCT + o)*SSP + w*HH + ch*8;
    bf16x8 vv = *(const bf16x8*)src;
    bf16x8 rv;
    #pragma unroll
    for(int e=0;e<8;e++) rv[e] = f2s(pa*s2f(vv[e])+pb);
    if(!isV){
      short* dst = (rid<16)? qA : kA;
      #pragma unroll
      for(int e=0;e<8;e++) dst[(ch*8+e)*STQ + c] = rv[e];
    } else {
      *(bf16x8*)(vB + c*STA + ch*8) = rv;
      if(ch==0){
        *(bf16x8*)(vB + c*STA + 56) = z8;
        *(bf16x8*)(vB + c*STA + 64) = z8;
      }
    }
  } else {
    int z = tid-448;
    if(z<48){
      short* arr = (z<24)? qA : kA;
      int zz = (z<24)? z : z-24;
      *(int4*)((char*)arr + 56*STQ*2 + zz*16) = (int4){0,0,0,0};
    }
  }
  __syncthreads();

  for(int T=W; T<56; T+=8){
    int isK = (T>=28);
    int t2 = isK ? T-28 : T;
    int ti = t2/7, td = t2-7*ti;
    int i0 = ti*16, d0 = td*16;
    const short* aBase = isK ? kA : qA;
    const short* bBase = isK ? rkB : rqB;
    bf16x8 av = (l4<2)? *(const bf16x8*)(aBase + (i0+l15)*STQ + l4*8) : z8;
    bf16x8 bv = (l4<2)? *(const bf16x8*)(bBase + (d0+l15)*24 + l4*8) : z8;
    f32x4 acc = {0.f,0.f,0.f,0.f};
    acc = __builtin_amdgcn_mfma_f32_16x16x32_bf16(av, bv, acc, 0,0,0);
    short* dst = isK ? krT : qrT;
    int d = d0 + l15;
    int ib = i0 + l4*4;
    if(ib < 53){
      unsigned* wp = (unsigned*)(dst + d*SQT + ib);
      wp[0] = pk2(acc[0], acc[1]);
      wp[1] = pk2(acc[2], acc[3]);
    }
  }
  __syncthreads();

  float e8[8];
  #pragma unroll
  for(int tt=0; tt<2; tt++){
    int T = W + 8*tt;
    int ti = T>>2, tj = T&3;
    int i0 = ti*16, j0 = tj*16;
    bf16x8 av = (l4<2)? *(const bf16x8*)(qA + (i0+l15)*STQ + l4*8) : z8;
    bf16x8 bv = (l4<2)? *(const bf16x8*)(kA + (j0+l15)*STQ + l4*8) : z8;
    f32x4 acc = {0.f,0.f,0.f,0.f};
    acc = __builtin_amdgcn_mfma_f32_16x16x32_bf16(av, bv, acc, 0,0,0);
    int j = j0 + l15;
    int jv = (j < HH);
    #pragma unroll
    for(int r=0;r<4;r++){
      int i = i0 + l4*4 + r;
      float vqr = s2f(qrT[(i-j+55)*SQT + i]);
      float vkr = s2f(krT[(j-i+55)*SQT + j]);
      float v = aqk*acc[r] + aqr*vqr + akr*vkr + bsum;
      e8[tt*4+r] = jv ? __expf(v) : 0.f;
    }
  }
  __syncthreads();

  for(int idx=tid; idx<ZERO_I4; idx+=512) ((int4*)sm)[idx] = (int4){0,0,0,0};
  __syncthreads();

  short* simA = (short*)(sm + OFF_SIMA);
  short* simSh = (short*)(sm + OFF_SIMSH);
  #pragma unroll
  for(int tt=0; tt<2; tt++){
    int T = W + 8*tt;
    int ti = T>>2, tj = T&3;
    int j = tj*16 + l15;
    #pragma unroll
    for(int r=0;r<4;r++){
      int i = ti*16 + l4*4 + r;
      if(i<HH && j<HH){
        short pv = f2s(e8[tt*4+r]);
        simA[i*STA + j] = pv;
        simSh[i*STSH + (i+55-j)] = pv;
      }
    }
  }
  __syncthreads();

  if(W>=4){
    int i0 = (W-4)*16;
    const short one_s = 0x3F80;
    bf16x8 onesv = {one_s,one_s,one_s,one_s,one_s,one_s,one_s,one_s};
    bf16x8 bv = (l15==0)? onesv : z8;
    f32x4 acc = {0.f,0.f,0.f,0.f};
    #pragma unroll
    for(int ks=0; ks<2; ks++){
      bf16x8 av = *(const bf16x8*)(simA + (i0+l15)*STA + ks*32 + l4*8);
      acc = __builtin_amdgcn_mfma_f32_16x16x32_bf16(av, bv, acc, 0,0,0);
    }
    if(l15==0){
      #pragma unroll
      for(int r=0;r<4;r++){
        int i = i0 + l4*4 + r;
        if(i<HH) rfacL[i] = 1.0f/acc[r];
      }
    }
  }

  f32x4 accJ[2];
  #pragma unroll
  for(int jt=0; jt<2; jt++){
    int T = W + 8*jt;
    int isE = (T>=8);
    int tt = T&7;
    int ti = tt>>1, tc = tt&1;
    int i0 = ti*16, c0 = tc*16;
    f32x4 acc = {0.f,0.f,0.f,0.f};
    if(!isE){
      #pragma unroll
      for(int ks=0; ks<2; ks++){
        int j0 = ks*32;
        bf16x8 av = *(const bf16x8*)(simA + (i0+l15)*STA + j0 + l4*8);
        bf16x8 bv = *(const bf16x8*)(vB + (c0+l15)*STA + j0 + l4*8);
        acc = __builtin_amdgcn_mfma_f32_16x16x32_bf16(av, bv, acc, 0,0,0);
      }
    } else {
      #pragma unroll
      for(int ks=0; ks<4; ks++){
        int d0 = ks*32;
        bf16x8 av = *(const bf16x8*)(simSh + (i0+l15)*STSH + d0 + l4*8);
        bf16x8 bv = *(const bf16x8*)(rvBg + (c0+l15)*128 + d0 + l4*8);
        acc = __builtin_amdgcn_mfma_f32_16x16x32_bf16(av, bv, acc, 0,0,0);
      }
    }
    accJ[jt] = acc;
  }
  __syncthreads();

  float* ostS = (float*)(sm + OFF_OST);
  float* ostQ = ostS + 64;
  #pragma unroll
  for(int jt=0; jt<2; jt++){
    int T = W + 8*jt;
    int isE = (T>=8);
    int tt = T&7;
    int ti = tt>>1, tc = tt&1;
    int i0 = ti*16, c0 = tc*16;
    f32x4 acc = accJ[jt];
    int c = c0 + l15;
    int ib = i0 + l4*4;
    float s1=0.f, s2=0.f;
    if(ib+3 < HH){
      float4 rf = *(const float4*)(rfacL + ib);
      acc[0]*=rf.x; acc[1]*=rf.y; acc[2]*=rf.z; acc[3]*=rf.w;
      size_t gb = ((((size_t)n*WW + w)*GG + g)*GPF + c)*HH;
      bf16* dst = isE ? svew : svw;
      short4 pk;
      pk.x = f2s(acc[0]); pk.y = f2s(acc[1]); pk.z = f2s(acc[2]); pk.w = f2s(acc[3]);
      *reinterpret_cast<short4*>(dst + gb + ib) = pk;
      #pragma unroll
      for(int r=0;r<4;r++){ s1 += acc[r]; s2 += acc[r]*acc[r]; }
    }
    int u = 2*c + (isE?1:0);
    atomicAdd(&ostS[u], s1);
    atomicAdd(&ostQ[u], s2);
  }
  __syncthreads();
  if(tid<64){
    atomicAdd(&fws[F_OSUM + g*64 + tid], ostS[tid]);
    atomicAdd(&fws[F_OSQ  + g*64 + tid], ostQ[tid]);
  }
  // last-block finalize (out BN a,b)
  __threadfence();
  if(tid==0) lastA = atomicAdd((unsigned*)&fws[F_CNT_A], 1u);
  __syncthreads();
  if(lastA == 7167u && tid<512){
    int o = tid;
    float s = aload(&fws[F_OSUM+o]);
    float q = aload(&fws[F_OSQ+o]);
    float m = s*(1.0f/CNT_PROJ);
    float var = q*(1.0f/CNT_PROJ) - m*m;
    float a = og[o]*rsqrtf(var+EPSV);
    fws[F_OA+o]=a; fws[F_OB+o]=ob[o]-m*a;
  }
}

// ============ K7: combine + transpose ============
__global__ __launch_bounds__(256) void k_out(const bf16* __restrict__ svw, const bf16* __restrict__ svew,
                                             const float* __restrict__ fws, float* __restrict__ out){
  int oc = blockIdx.x, n = blockIdx.y;
  int g = oc>>5, c = oc&31;
  __shared__ float s1l[WW][57], s2l[WW][57];
  int t=threadIdx.x;
  for(int idx=t; idx<392; idx+=256){
    int w = idx/7, hc = idx-w*7;
    size_t base = (((size_t)(n*WW+w)*GG+g)*GPF+c)*HH + hc*8;
    bf16x8 v1 = *(const bf16x8*)(svw+base);
    bf16x8 v2 = *(const bf16x8*)(svew+base);
    #pragma unroll
    for(int e=0;e<8;e++){
      s1l[w][hc*8+e] = s2f(v1[e]);
      s2l[w][hc*8+e] = s2f(v2[e]);
    }
  }
  int ch0 = g*64+2*c;
  float a1=fws[F_OA+ch0], b1=fws[F_OB+ch0], a2=fws[F_OA+ch0+1], b2=fws[F_OB+ch0+1];
  __syncthreads();
  size_t obase = (size_t)(n*CCH+oc)*SSP;
  for(int idx=t; idx<784; idx+=256){
    int h = idx/14, w4 = (idx-h*14)*4;
    float4 o4;
    o4.x = a1*s1l[w4+0][h]+b1 + a2*s2l[w4+0][h]+b2;
    o4.y = a1*s1l[w4+1][h]+b1 + a2*s2l[w4+1][h]+b2;
    o4.z = a1*s1l[w4+2][h]+b1 + a2*s2l[w4+2][h]+b2;
    o4.w = a1*s1l[w4+3][h]+b1 + a2*s2l[w4+3][h]+b2;
    *reinterpret_cast<float4*>(out + obase + (size_t)h*WW + w4) = o4;
  }
}

extern "C" void kernel_launch(void* const* d_in, const int* in_sizes, int n_in,
                              void* d_out, int out_size, void* d_ws, size_t ws_size,
                              hipStream_t stream) {
  const float* x    = (const float*)d_in[0];
  const float* xd   = (const float*)d_in[1];
  const float* carw = (const float*)d_in[2];
  const float* carb = (const float*)d_in[3];
  const float* cadw = (const float*)d_in[4];
  const float* cadb = (const float*)d_in[5];
  const float* qw   = (const float*)d_in[6];
  const float* kw   = (const float*)d_in[7];
  const float* vw   = (const float*)d_in[8];
  const float* bnqg = (const float*)d_in[9];
  const float* bnqb = (const float*)d_in[10];
  const float* bnkg = (const float*)d_in[11];
  const float* bnkb = (const float*)d_in[12];
  const float* bnvg = (const float*)d_in[13];
  const float* bnvb = (const float*)d_in[14];
  const float* bnsg = (const float*)d_in[15];
  const float* bnsb = (const float*)d_in[16];
  const float* bnog = (const float*)d_in[17];
  const float* bnob = (const float*)d_in[18];
  const float* rel  = (const float*)d_in[19];
  float* out = (float*)d_out;

  char* ws = (char*)d_ws;
  const size_t PROJ_BYTES = (size_t)NN*OCT*SSP*sizeof(bf16);
  const size_t XT_BYTES   = (size_t)NN*SSP*CCH*sizeof(bf16);
  const size_t WQS_BYTES  = (size_t)NN*128*256*sizeof(bf16);
  const size_t VWB_BYTES  = (size_t)256*256*sizeof(bf16);
  const size_t FWS_BYTES  = (size_t)((F_TOT+3)/4*4)*sizeof(float);
  const size_t TB_BYTES   = (size_t)((T_TOT+7)/8*8)*sizeof(short);

  size_t off = 0;
  bf16* proj = (bf16*)(ws + off); off += PROJ_BYTES;
  bf16* xT   = (bf16*)(ws + off); size_t off_xT = off; off += XT_BYTES;
  bf16* xdT  = (bf16*)(ws + off); size_t off_xdT = off; off += XT_BYTES;
  bf16* xfT  = (bf16*)(ws + off); off += XT_BYTES;
  bf16* wqs  = (bf16*)(ws + off); off += WQS_BYTES;
  bf16* wks  = (bf16*)(ws + off); off += WQS_BYTES;
  bf16* vwb  = (bf16*)(ws + off); off += VWB_BYTES;
  float* fws = (float*)(ws + off); off += FWS_BYTES;
  short* tb  = (short*)(ws + off); off += TB_BYTES;
  if (ws_size < off) return;
  bf16* svw  = (bf16*)(ws + off_xT);
  bf16* svew = (bf16*)(ws + off_xdT);

  hipMemsetAsync(fws, 0, (size_t)F_ACC_END*sizeof(float), stream);
  k_prep<<<dim3(98,NN), 256, 0, stream>>>(x, xd, rel, fws, tb, xT, xdT, xfT);
  k_chanatt<<<NN, 256, 0, stream>>>(carw, carb, cadw, cadb, fws);
  k_wprep<<<17, 256, 0, stream>>>(qw, kw, vw, fws, wqs, wks, vwb);
  k_gemm<<<dim3(3136), 256, 0, stream>>>(xT, xdT, xfT, wqs, wks, vwb,
                                         bnqg, bnqb, bnkg, bnkb, bnvg, bnvb, fws, proj);
  k_simstat<<<dim3(8,NN,GG), 256, 0, stream>>>(proj, tb, bnsg, bnsb, fws);
  k_att<<<dim3(GG,WW,NN), 512, 0, stream>>>(proj, tb, bnog, bnob, fws, svw, svew);
  k_out<<<dim3(CCH,NN), 256, 0, stream>>>(svw, svew, fws, out);
}

// Round 14
// 429.677 us; speedup vs baseline: 5.3476x; 5.3476x over previous
//
#include <hip/hip_runtime.h>
#include <hip/hip_bf16.h>
#include <math.h>

typedef __hip_bfloat16 bf16;
typedef __attribute__((ext_vector_type(8))) short bf16x8;
typedef __attribute__((ext_vector_type(4))) float f32x4;

#define NN 16
#define CCH 256
#define HH 56
#define WW 56
#define SSP 3136
#define GG 8
#define GPH 16
#define GPF 32
#define OCT 512
#define RL 111
#define EPSV 1e-5f
#define CNT_PROJ 50176.0f
#define CNT_SIM  2809856.0f

__device__ __forceinline__ float bf2f(bf16 v){ return __bfloat162float(v); }
__device__ __forceinline__ bf16 f2bf(float v){ return __float2bfloat16(v); }
__device__ __forceinline__ short f2s(float f){ bf16 h = __float2bfloat16(f); return __builtin_bit_cast(short, h); }
__device__ __forceinline__ float s2f(short s){ bf16 h = __builtin_bit_cast(bf16, s); return __bfloat162float(h); }
__device__ __forceinline__ unsigned pk2(float a, float b){
  return (unsigned)(unsigned short)f2s(a) | ((unsigned)(unsigned short)f2s(b)<<16);
}

__device__ __forceinline__ void gl16(const void* g, void* l){
  __builtin_amdgcn_global_load_lds((const __attribute__((address_space(1))) void*)g,
                                   (__attribute__((address_space(3))) void*)l, 16, 0, 0);
}

// ---- f32 workspace region layout (float indices) ----
#define F_PR 0
#define F_PD 4096
#define F_SR 8192
#define F_SD 12288
#define F_PSUM 16384
#define F_PSQ  16896
#define F_PA   17408
#define F_PB   17920
#define F_SSUM 18432
#define F_SSQ  18464
#define F_SA   18496
#define F_SB   18528
#define F_OSUM 18560
#define F_OSQ  19072
#define F_OA   19584
#define F_OB   20096
#define F_ACC_END 20608
#define F_TOT  20608
// bf16 table region (shorts)
#define T_RQ 0        // [112][24]
#define T_RK 2688     // [112][24]
#define T_RV 5376     // [32][128]
#define T_TOT 9472

// k_att LDS layout (bytes)
#define STQ 24
#define SQT 58
#define STA 72
#define STSH 136
#define STG 72
#define OFF_QA   0
#define OFF_KA   3072
#define OFF_QR   6144
#define OFF_KR   19136
#define OFF_VB   32128
#define OFF_FAC  36736
#define OFF_OST  36992
#define SMSZ     37504
#define OFF_SIMA 0
#define OFF_SIMSH 9216
#define ZERO_I4  1664

// k_simstat LDS (shorts per buffer)
#define SB_QA 0
#define SB_KA 1536
#define SB_QG 3072
#define SB_KG 4224
#define SB_TOT 5376
#define SB_ZI4 1344

// ============ K1: prep (+ tables in block (0,0)) ============
__global__ __launch_bounds__(256) void k_prep(const float* __restrict__ x, const float* __restrict__ xd,
                                              const float* __restrict__ rel,
                                              float* __restrict__ fws, short* __restrict__ tb,
                                              bf16* __restrict__ xT, bf16* __restrict__ xdT, bf16* __restrict__ xfT){
  __shared__ __align__(16) short tx[32*264];
  __shared__ __align__(16) short td[32*264];
  __shared__ __align__(16) short tf[32*264];
  int s0 = blockIdx.x*32, n = blockIdx.y;
  int t = threadIdx.x;
  int si = t & 31, cg = t >> 5;
  for(int cc=0; cc<CCH; cc+=8){
    int c = cc + cg;
    size_t gi = ((size_t)n*CCH + c)*SSP + s0 + si;
    float vx = x[gi], vd = xd[gi];
    tx[si*264+c] = f2s(vx);
    td[si*264+c] = f2s(vd);
    tf[si*264+c] = f2s(vx*vd);
  }
  __syncthreads();
  {
    float s1=0.f, s2=0.f;
    for(int sr=0; sr<32; sr++){ s1 += s2f(tx[sr*264+t]); s2 += s2f(td[sr*264+t]); }
    atomicAdd(&fws[F_PR+n*CCH+t], s1);
    atomicAdd(&fws[F_PD+n*CCH+t], s2);
  }
  size_t rbase = (size_t)n*SSP;
  for(int idx=t; idx<32*32; idx+=256){
    int sr2 = idx>>5, ch = idx&31;
    int sp = s0 + sr2;
    int s2 = (sp%WW)*HH + sp/WW;
    float4 v1 = *(const float4*)(tx + sr2*264 + ch*8);
    float4 v2 = *(const float4*)(td + sr2*264 + ch*8);
    float4 v3 = *(const float4*)(tf + sr2*264 + ch*8);
    *reinterpret_cast<float4*>(xT  + (rbase + s2)*CCH + ch*8) = v1;
    *reinterpret_cast<float4*>(xdT + (rbase + s2)*CCH + ch*8) = v2;
    *reinterpret_cast<float4*>(xfT + (rbase + s2)*CCH + ch*8) = v3;
  }
  if(blockIdx.x==0 && blockIdx.y==0){
    for(int idx=t; idx<112*24; idx+=256){
      int d = idx/24, c = idx - d*24;
      short vq=0, vk=0;
      if(c<16 && d<RL){ vq = f2s(rel[c*RL+d]); vk = f2s(rel[(16+c)*RL+d]); }
      tb[T_RQ+idx]=vq; tb[T_RK+idx]=vk;
    }
    for(int idx=t; idx<32*128; idx+=256){
      int c = idx>>7, d = idx&127;
      short v=0;
      if(d<RL) v = f2s(rel[(32+c)*RL+d]);
      tb[T_RV+idx]=v;
    }
  }
}

// ============ K2: channel attention scales ============
__global__ __launch_bounds__(256) void k_chanatt(const float* __restrict__ wr, const float* __restrict__ br,
                                                 const float* __restrict__ wd, const float* __restrict__ bd,
                                                 float* __restrict__ fws){
  int c = threadIdx.x, n = blockIdx.x;
  __shared__ float red[256];
  __shared__ float prl[256], pdl[256];
  prl[c]=fws[F_PR+n*CCH+c]*(1.f/SSP); pdl[c]=fws[F_PD+n*CCH+c]*(1.f/SSP);
  __syncthreads();
  float dr=br[c], dd=bd[c];
  for(int k=0;k<CCH;k++){ dr = fmaf(prl[k], wr[c*CCH+k], dr); dd = fmaf(pdl[k], wd[c*CCH+k], dd); }
  dr = fmaxf(dr,0.f); dd = fmaxf(dd,0.f);
  float car = 1.f/(1.f+expf(-dr));
  float cad = 1.f/(1.f+expf(-dd));
  float tv = car+cad;
  red[c]=tv; __syncthreads();
  for(int st=128;st>0;st>>=1){ if(c<st) red[c]=fmaxf(red[c],red[c+st]); __syncthreads(); }
  float mx = red[0]; __syncthreads();
  float e = expf(tv-mx);
  red[c]=e; __syncthreads();
  for(int st=128;st>0;st>>=1){ if(c<st) red[c]+=red[c+st]; __syncthreads(); }
  float co = e/red[0];
  fws[F_SR+n*CCH+c] = co+car;
  fws[F_SD+n*CCH+c] = co+cad;
}

// ============ K3: weight prep ============
__global__ __launch_bounds__(256) void k_wprep(const float* __restrict__ qw, const float* __restrict__ kw,
                                               const float* __restrict__ vw, const float* __restrict__ fws,
                                               bf16* __restrict__ wqs, bf16* __restrict__ wks, bf16* __restrict__ vwb){
  int b = blockIdx.x, t = threadIdx.x;
  if(b<16){
    const float* sr = fws + F_SR + b*CCH;
    const float* sd = fws + F_SD + b*CCH;
    for(int idx=t; idx<128*256; idx+=256){
      int c = idx & 255;
      wqs[b*32768+idx] = f2bf(qw[idx]*sr[c]);
      wks[b*32768+idx] = f2bf(kw[idx]*sd[c]);
    }
  } else {
    for(int idx=t; idx<256*256; idx+=256) vwb[idx] = f2bf(vw[idx]);
  }
}

// ============ K4: MFMA projection GEMM — 64s x 128o tiles (A staged once per o-pair) ============
__global__ __launch_bounds__(256) void k_gemm(const bf16* __restrict__ xT, const bf16* __restrict__ xdT,
                                              const bf16* __restrict__ xfT,
                                              const bf16* __restrict__ wqs, const bf16* __restrict__ wks,
                                              const bf16* __restrict__ vwb,
                                              float* __restrict__ fws, bf16* __restrict__ proj){
  __shared__ __align__(16) char sm[50176];   // A0 8K | A1 8K | B0 16K | B1 16K | sst 1K
  int bid = blockIdx.x;
  int sw = (bid & 7)*392 + (bid >> 3);       // 3136 = 8*392
  int p = sw & 3;
  int rest = sw >> 2;
  int s_t = rest % 49;
  int n   = rest / 49;
  int s0g = s_t*64;

  const bf16* Ag = (p==0 ? xT : (p==1 ? xdT : xfT)) + (size_t)n*SSP*CCH;
  const bf16* Wg = (p==0) ? (wqs + (size_t)n*32768)
                 : (p==1) ? (wks + (size_t)n*32768)
                          : (vwb + (size_t)(p-2)*128*256);

  int tid = threadIdx.x;
  int w = tid>>6, lane = tid&63;
  int l15 = lane & 15, l4 = lane >> 4;

  float* sst = (float*)(sm + 49152);
  sst[tid]=0.f;

  f32x4 acc[2][4];
  #pragma unroll
  for(int f=0;f<2;f++)
    #pragma unroll
    for(int e=0;e<4;e++) acc[f][e]=(f32x4){0,0,0,0};

  auto stage = [&](int b, int kk){
    #pragma unroll
    for(int j=0;j<2;j++){
      int rowstart = w*16 + j*8;
      int row = rowstart + (lane>>3);
      int ch  = (lane&7) ^ (row&7);
      gl16(Ag + (size_t)(s0g + row)*CCH + kk*64 + ch*8, sm + (b?8192:0) + rowstart*128);
    }
    #pragma unroll
    for(int j=0;j<4;j++){
      int rowstart = w*32 + j*8;
      int row = rowstart + (lane>>3);
      int ch  = (lane&7) ^ (row&7);
      gl16(Wg + (size_t)row*CCH + kk*64 + ch*8, sm + 16384 + (b?16384:0) + rowstart*128);
    }
  };

  stage(0,0);
  __syncthreads();
  int cur=0;
  int sl0 = (w&1)*32, ol0 = (w>>1)*64;
  for(int kk=0;kk<4;kk++){
    if(kk<3) stage(cur^1, kk+1);
    const short* Ab = (const short*)(sm + (cur?8192:0));
    const short* Bb = (const short*)(sm + 16384 + (cur?16384:0));
    #pragma unroll
    for(int kh=0;kh<2;kh++){
      bf16x8 a[2], b[4];
      #pragma unroll
      for(int f=0;f<2;f++){
        int sr = sl0 + f*16 + l15;
        int chv = (kh*4 + l4) ^ (sr&7);
        a[f] = *(const bf16x8*)(Ab + sr*64 + chv*8);
      }
      #pragma unroll
      for(int e=0;e<4;e++){
        int orw = ol0 + e*16 + l15;
        int chv = (kh*4 + l4) ^ (orw&7);
        b[e] = *(const bf16x8*)(Bb + orw*64 + chv*8);
      }
      #pragma unroll
      for(int f=0;f<2;f++)
        #pragma unroll
        for(int e=0;e<4;e++)
          acc[f][e] = __builtin_amdgcn_mfma_f32_16x16x32_bf16(a[f], b[e], acc[f][e], 0,0,0);
    }
    __syncthreads();
    cur ^= 1;
  }

  #pragma unroll
  for(int e=0;e<4;e++){
    float s1=0.f, s2=0.f;
    #pragma unroll
    for(int f=0;f<2;f++)
      #pragma unroll
      for(int r=0;r<4;r++){ float v=acc[f][e][r]; s1+=v; s2+=v*v; }
    s1 += __shfl_xor(s1,16); s2 += __shfl_xor(s2,16);
    s1 += __shfl_xor(s1,32); s2 += __shfl_xor(s2,32);
    if(l4==0){
      int ol = ol0 + e*16 + l15;
      atomicAdd(&sst[ol], s1);
      atomicAdd(&sst[128+ol], s2);
    }
  }
  #pragma unroll
  for(int f=0;f<2;f++)
    #pragma unroll
    for(int e=0;e<4;e++){
      int sbase = s0g + (w&1)*32 + f*16 + l4*4;
      int o = p*128 + ol0 + e*16 + l15;
      short4 pk;
      pk.x = f2s(acc[f][e][0]); pk.y = f2s(acc[f][e][1]);
      pk.z = f2s(acc[f][e][2]); pk.w = f2s(acc[f][e][3]);
      *reinterpret_cast<short4*>(proj + ((size_t)n*OCT + o)*SSP + sbase) = pk;
    }
  __syncthreads();
  if(tid<128){
    int og = p*128 + tid;
    atomicAdd(&fws[F_PSUM+og], sst[tid]);
    atomicAdd(&fws[F_PSQ+og],  sst[128+tid]);
  }
}

// ============ K5: finalize proj BN ============
__global__ void k_finproj(const float* qg,const float* qb,const float* kg,const float* kb,
                          const float* vg,const float* vb, float* fws){
  int o = threadIdx.x;
  float m = fws[F_PSUM+o]*(1.0f/CNT_PROJ);
  float var = fws[F_PSQ+o]*(1.0f/CNT_PROJ) - m*m;
  float g,b;
  if(o<128){ g=qg[o]; b=qb[o]; }
  else if(o<256){ g=kg[o-128]; b=kb[o-128]; }
  else { g=vg[o-256]; b=vb[o-256]; }
  float a = g*rsqrtf(var+EPSV);
  fws[F_PA+o]=a; fws[F_PB+o]=b-m*a;
}

// ============ K6: sim-BN stats — 7 w per block, double-buffered ============
__global__ __launch_bounds__(256) void k_simstat(const bf16* __restrict__ proj,
                                                 const short* __restrict__ tb,
                                                 float* __restrict__ fws){
  __shared__ __align__(16) short smS[2*SB_TOT];
  __shared__ float redW[4][4];
  __shared__ float red2[2];
  int wq = blockIdx.x, n = blockIdx.y, g = blockIdx.z;
  int t = threadIdx.x;
  int W = t>>6, lane = t&63;
  int l15 = lane&15, l4 = lane>>4;
  const short* rqB = tb + T_RQ;
  const short* rkB = tb + T_RK;
  const bf16x8 z8 = {};

  for(int i=t; i<SB_ZI4; i+=256) ((int4*)smS)[i] = (int4){0,0,0,0};

  int isLoader = (t<224);
  int rid = t/7, ch = t - rid*7;
  int isK = rid>=16, c = rid&15;
  int o = (isK?128:0) + g*GPH + c;
  float pa=0.f, pb=0.f;
  const bf16* gsrc = proj + ((size_t)n*OCT+o)*SSP + ch*8;
  if(isLoader){ pa = fws[F_PA+o]; pb = fws[F_PB+o]; }
  int w0 = wq*7;

  auto stageWrite = [&](short* buf, bf16x8 vv){
    bf16x8 rv;
    #pragma unroll
    for(int e=0;e<8;e++) rv[e] = f2s(pa*s2f(vv[e])+pb);
    short* dA = buf + (isK? SB_KA : SB_QA);
    #pragma unroll
    for(int e=0;e<8;e++) dA[(ch*8+e)*STQ + c] = rv[e];
    short* gRow = buf + (isK? SB_KG : SB_QG) + c*STG;
    *(bf16x8*)(gRow + ch*8) = rv;
  };

  bf16x8 ld = z8;
  if(isLoader) ld = *(const bf16x8*)(gsrc + (size_t)w0*HH);
  __syncthreads();
  if(isLoader) stageWrite(smS, ld);
  __syncthreads();

  float sQ=0.f,qQ=0.f,sK=0.f,qK=0.f,pSS=0.f,pS=0.f;
  #pragma unroll 1
  for(int it=0; it<7; it++){
    bf16x8 nx = z8;
    if(it<6 && isLoader) nx = *(const bf16x8*)(gsrc + (size_t)(w0+it+1)*HH);
    const short* buf = smS + (it&1)*SB_TOT;
    const short* qA = buf + SB_QA;
    const short* kA = buf + SB_KA;
    const short* qG = buf + SB_QG;
    const short* kG = buf + SB_KG;

    for(int T=W; T<56; T+=4){
      int tk = (T>=28);
      int t2 = tk ? T-28 : T;
      int ti = t2/7, td = t2-7*ti;
      int i0 = ti*16, d0 = td*16;
      const short* aBase = tk ? kA : qA;
      const short* bBase = tk ? rkB : rqB;
      bf16x8 av = (l4<2)? *(const bf16x8*)(aBase + (i0+l15)*STQ + l4*8) : z8;
      bf16x8 bv = (l4<2)? *(const bf16x8*)(bBase + (d0+l15)*24 + l4*8) : z8;
      f32x4 acc = {0.f,0.f,0.f,0.f};
      acc = __builtin_amdgcn_mfma_f32_16x16x32_bf16(av, bv, acc, 0,0,0);
      int d = d0 + l15;
      #pragma unroll
      for(int r=0;r<4;r++){
        int i = i0 + l4*4 + r;
        int dmi = d - i;
        if(dmi>=0 && dmi<56){
          float v = acc[r];
          if(tk){ sK += v; qK += v*v; }
          else  { sQ += v; qQ += v*v; }
        }
      }
    }
    if(W==0){
      bf16x8 a0 = *(const bf16x8*)(qG + l15*STG + l4*8);
      bf16x8 a1 = *(const bf16x8*)(qG + l15*STG + 32 + l4*8);
      f32x4 gq = {0.f,0.f,0.f,0.f};
      gq = __builtin_amdgcn_mfma_f32_16x16x32_bf16(a0, a0, gq, 0,0,0);
      gq = __builtin_amdgcn_mfma_f32_16x16x32_bf16(a1, a1, gq, 0,0,0);
      bf16x8 b0 = *(const bf16x8*)(kG + l15*STG + l4*8);
      bf16x8 b1 = *(const bf16x8*)(kG + l15*STG + 32 + l4*8);
      f32x4 gk = {0.f,0.f,0.f,0.f};
      gk = __builtin_amdgcn_mfma_f32_16x16x32_bf16(b0, b0, gk, 0,0,0);
      gk = __builtin_amdgcn_mfma_f32_16x16x32_bf16(b1, b1, gk, 0,0,0);
      pSS += gq[0]*gk[0]+gq[1]*gk[1]+gq[2]*gk[2]+gq[3]*gk[3];
    } else if(W==1){
      float rsum = 0.f;
      if(lane<32){
        const short* row = (lane<16)? (qG + lane*STG) : (kG + (lane-16)*STG);
        #pragma unroll
        for(int i8=0;i8<7;i8++){
          bf16x8 v8 = *(const bf16x8*)(row + i8*8);
          #pragma unroll
          for(int e=0;e<8;e++) rsum += s2f(v8[e]);
        }
      }
      float kv = __shfl(rsum, (lane+16)&63);
      if(lane<16) pS += rsum*kv;
    }

    if(it<6){
      __syncthreads();
      if(isLoader) stageWrite(smS + ((it+1)&1)*SB_TOT, nx);
      __syncthreads();
    }
  }

  float b4[4] = {sQ,qQ,sK,qK};
  #pragma unroll
  for(int u=0;u<4;u++){
    float v = b4[u];
    #pragma unroll
    for(int msk=1;msk<64;msk<<=1) v += __shfl_xor(v,msk);
    if(lane==0) redW[W][u] = v;
  }
  if(W==0){
    float p = pSS;
    #pragma unroll
    for(int msk=1;msk<64;msk<<=1) p += __shfl_xor(p,msk);
    if(lane==0) red2[1] = p;
  } else if(W==1){
    float p = (lane<16)? pS : 0.f;
    #pragma unroll
    for(int msk=1;msk<16;msk<<=1) p += __shfl_xor(p,msk);
    if(lane==0) red2[0] = p;
  }
  __syncthreads();
  if(t<4){
    float s = redW[0][t]+redW[1][t]+redW[2][t]+redW[3][t];
    int tgt = (t==0)? (F_SSUM+8+g) : (t==1)? (F_SSQ+8+g) : (t==2)? (F_SSUM+16+g) : (F_SSQ+16+g);
    atomicAdd(&fws[tgt], s);
  } else if(t==4){
    atomicAdd(&fws[F_SSUM+g], red2[0]);
  } else if(t==5){
    atomicAdd(&fws[F_SSQ+g], red2[1]);
  }
}

__global__ void k_finsim(const float* sg, const float* sb, float* fws){
  int ch = threadIdx.x; if(ch>=24) return;
  float m = fws[F_SSUM+ch]*(1.0f/CNT_SIM);
  float var = fws[F_SSQ+ch]*(1.0f/CNT_SIM) - m*m;
  float a = sg[ch]*rsqrtf(var+EPSV);
  fws[F_SA+ch]=a; fws[F_SB+ch]=sb[ch]-m*a;
}

// ============ K7: main MFMA attention (max-free softmax; row-sums via MFMA ones-trick) ============
__global__ __launch_bounds__(512) void k_att(const bf16* __restrict__ proj,
                                             const short* __restrict__ tb,
                                             float* __restrict__ fws,
                                             bf16* __restrict__ svw, bf16* __restrict__ svew){
  __shared__ __align__(16) char sm[SMSZ];
  int g = blockIdx.x, w = blockIdx.y, n = blockIdx.z;
  int tid = threadIdx.x;
  int W = tid >> 6, lane = tid & 63;
  int l15 = lane & 15, l4 = lane >> 4;
  short* qA = (short*)(sm + OFF_QA);
  short* kA = (short*)(sm + OFF_KA);
  short* qrT = (short*)(sm + OFF_QR);
  short* krT = (short*)(sm + OFF_KR);
  short* vB  = (short*)(sm + OFF_VB);
  float* rfacL = (float*)(sm + OFF_FAC);
  const short* rqB = tb + T_RQ;
  const short* rkB = tb + T_RK;
  const short* rvBg = tb + T_RV;
  const float* PA = fws + F_PA;
  const float* PB = fws + F_PB;
  const bf16x8 z8 = {};

  float aqk = fws[F_SA+g], aqr = fws[F_SA+8+g], akr = fws[F_SA+16+g];
  float bsum = fws[F_SB+g]+fws[F_SB+8+g]+fws[F_SB+16+g];

  if(tid<128) ((float*)(sm+OFF_OST))[tid]=0.f;
  if(tid<448){
    int rid = tid/7, ch = tid - rid*7;
    int o, c, isV=0;
    if(rid<16){ c=rid; o = g*GPH + c; }
    else if(rid<32){ c=rid-16; o = 128 + g*GPH + c; }
    else { c=rid-32; o = 256 + g*GPF + c; isV=1; }
    float pa = PA[o], pb = PB[o];
    const bf16* src = proj + ((size_t)n*OCT + o)*SSP + w*HH + ch*8;
    bf16x8 vv = *(const bf16x8*)src;
    bf16x8 rv;
    #pragma unroll
    for(int e=0;e<8;e++) rv[e] = f2s(pa*s2f(vv[e])+pb);
    if(!isV){
      short* dst = (rid<16)? qA : kA;
      #pragma unroll
      for(int e=0;e<8;e++) dst[(ch*8+e)*STQ + c] = rv[e];
    } else {
      *(bf16x8*)(vB + c*STA + ch*8) = rv;
      if(ch==0){
        *(bf16x8*)(vB + c*STA + 56) = z8;
        *(bf16x8*)(vB + c*STA + 64) = z8;
      }
    }
  } else {
    int z = tid-448;
    if(z<48){
      short* arr = (z<24)? qA : kA;
      int zz = (z<24)? z : z-24;
      *(int4*)((char*)arr + 56*STQ*2 + zz*16) = (int4){0,0,0,0};
    }
  }
  __syncthreads();

  for(int T=W; T<56; T+=8){
    int isK = (T>=28);
    int t2 = isK ? T-28 : T;
    int ti = t2/7, td = t2-7*ti;
    int i0 = ti*16, d0 = td*16;
    const short* aBase = isK ? kA : qA;
    const short* bBase = isK ? rkB : rqB;
    bf16x8 av = (l4<2)? *(const bf16x8*)(aBase + (i0+l15)*STQ + l4*8) : z8;
    bf16x8 bv = (l4<2)? *(const bf16x8*)(bBase + (d0+l15)*24 + l4*8) : z8;
    f32x4 acc = {0.f,0.f,0.f,0.f};
    acc = __builtin_amdgcn_mfma_f32_16x16x32_bf16(av, bv, acc, 0,0,0);
    short* dst = isK ? krT : qrT;
    int d = d0 + l15;
    int ib = i0 + l4*4;
    if(ib < 53){
      unsigned* wp = (unsigned*)(dst + d*SQT + ib);
      wp[0] = pk2(acc[0], acc[1]);
      wp[1] = pk2(acc[2], acc[3]);
    }
  }
  __syncthreads();

  float e8[8];
  #pragma unroll
  for(int tt=0; tt<2; tt++){
    int T = W + 8*tt;
    int ti = T>>2, tj = T&3;
    int i0 = ti*16, j0 = tj*16;
    bf16x8 av = (l4<2)? *(const bf16x8*)(qA + (i0+l15)*STQ + l4*8) : z8;
    bf16x8 bv = (l4<2)? *(const bf16x8*)(kA + (j0+l15)*STQ + l4*8) : z8;
    f32x4 acc = {0.f,0.f,0.f,0.f};
    acc = __builtin_amdgcn_mfma_f32_16x16x32_bf16(av, bv, acc, 0,0,0);
    int j = j0 + l15;
    int jv = (j < HH);
    #pragma unroll
    for(int r=0;r<4;r++){
      int i = i0 + l4*4 + r;
      float vqr = s2f(qrT[(i-j+55)*SQT + i]);
      float vkr = s2f(krT[(j-i+55)*SQT + j]);
      float v = aqk*acc[r] + aqr*vqr + akr*vkr + bsum;
      e8[tt*4+r] = jv ? __expf(v) : 0.f;
    }
  }
  __syncthreads();

  for(int idx=tid; idx<ZERO_I4; idx+=512) ((int4*)sm)[idx] = (int4){0,0,0,0};
  __syncthreads();

  short* simA = (short*)(sm + OFF_SIMA);
  short* simSh = (short*)(sm + OFF_SIMSH);
  #pragma unroll
  for(int tt=0; tt<2; tt++){
    int T = W + 8*tt;
    int ti = T>>2, tj = T&3;
    int j = tj*16 + l15;
    #pragma unroll
    for(int r=0;r<4;r++){
      int i = ti*16 + l4*4 + r;
      if(i<HH && j<HH){
        short pv = f2s(e8[tt*4+r]);
        simA[i*STA + j] = pv;
        simSh[i*STSH + (i+55-j)] = pv;
      }
    }
  }
  __syncthreads();

  if(W>=4){
    int i0 = (W-4)*16;
    const short one_s = 0x3F80;
    bf16x8 onesv = {one_s,one_s,one_s,one_s,one_s,one_s,one_s,one_s};
    bf16x8 bv = (l15==0)? onesv : z8;
    f32x4 acc = {0.f,0.f,0.f,0.f};
    #pragma unroll
    for(int ks=0; ks<2; ks++){
      bf16x8 av = *(const bf16x8*)(simA + (i0+l15)*STA + ks*32 + l4*8);
      acc = __builtin_amdgcn_mfma_f32_16x16x32_bf16(av, bv, acc, 0,0,0);
    }
    if(l15==0){
      #pragma unroll
      for(int r=0;r<4;r++){
        int i = i0 + l4*4 + r;
        if(i<HH) rfacL[i] = 1.0f/acc[r];
      }
    }
  }

  f32x4 accJ[2];
  #pragma unroll
  for(int jt=0; jt<2; jt++){
    int T = W + 8*jt;
    int isE = (T>=8);
    int tt = T&7;
    int ti = tt>>1, tc = tt&1;
    int i0 = ti*16, c0 = tc*16;
    f32x4 acc = {0.f,0.f,0.f,0.f};
    if(!isE){
      #pragma unroll
      for(int ks=0; ks<2; ks++){
        int j0 = ks*32;
        bf16x8 av = *(const bf16x8*)(simA + (i0+l15)*STA + j0 + l4*8);
        bf16x8 bv = *(const bf16x8*)(vB + (c0+l15)*STA + j0 + l4*8);
        acc = __builtin_amdgcn_mfma_f32_16x16x32_bf16(av, bv, acc, 0,0,0);
      }
    } else {
      #pragma unroll
      for(int ks=0; ks<4; ks++){
        int d0 = ks*32;
        bf16x8 av = *(const bf16x8*)(simSh + (i0+l15)*STSH + d0 + l4*8);
        bf16x8 bv = *(const bf16x8*)(rvBg + (c0+l15)*128 + d0 + l4*8);
        acc = __builtin_amdgcn_mfma_f32_16x16x32_bf16(av, bv, acc, 0,0,0);
      }
    }
    accJ[jt] = acc;
  }
  __syncthreads();

  float* ostS = (float*)(sm + OFF_OST);
  float* ostQ = ostS + 64;
  #pragma unroll
  for(int jt=0; jt<2; jt++){
    int T = W + 8*jt;
    int isE = (T>=8);
    int tt = T&7;
    int ti = tt>>1, tc = tt&1;
    int i0 = ti*16, c0 = tc*16;
    f32x4 acc = accJ[jt];
    int c = c0 + l15;
    int ib = i0 + l4*4;
    float s1=0.f, s2=0.f;
    if(ib+3 < HH){
      float4 rf = *(const float4*)(rfacL + ib);
      acc[0]*=rf.x; acc[1]*=rf.y; acc[2]*=rf.z; acc[3]*=rf.w;
      size_t gb = ((((size_t)n*WW + w)*GG + g)*GPF + c)*HH;
      bf16* dst = isE ? svew : svw;
      short4 pk;
      pk.x = f2s(acc[0]); pk.y = f2s(acc[1]); pk.z = f2s(acc[2]); pk.w = f2s(acc[3]);
      *reinterpret_cast<short4*>(dst + gb + ib) = pk;
      #pragma unroll
      for(int r=0;r<4;r++){ s1 += acc[r]; s2 += acc[r]*acc[r]; }
    }
    int u = 2*c + (isE?1:0);
    atomicAdd(&ostS[u], s1);
    atomicAdd(&ostQ[u], s2);
  }
  __syncthreads();
  if(tid<64){
    atomicAdd(&fws[F_OSUM + g*64 + tid], ostS[tid]);
    atomicAdd(&fws[F_OSQ  + g*64 + tid], ostQ[tid]);
  }
}

__global__ void k_finout(const float* og, const float* ob, float* fws){
  int o = threadIdx.x;
  float m = fws[F_OSUM+o]*(1.0f/CNT_PROJ);
  float var = fws[F_OSQ+o]*(1.0f/CNT_PROJ) - m*m;
  float a = og[o]*rsqrtf(var+EPSV);
  fws[F_OA+o]=a; fws[F_OB+o]=ob[o]-m*a;
}

__global__ __launch_bounds__(256) void k_out(const bf16* __restrict__ svw, const bf16* __restrict__ svew,
                                             const float* __restrict__ fws, float* __restrict__ out){
  int oc = blockIdx.x, n = blockIdx.y;
  int g = oc>>5, c = oc&31;
  __shared__ float s1l[WW][57], s2l[WW][57];
  int t=threadIdx.x;
  for(int idx=t; idx<392; idx+=256){
    int w = idx/7, hc = idx-w*7;
    size_t base = (((size_t)(n*WW+w)*GG+g)*GPF+c)*HH + hc*8;
    bf16x8 v1 = *(const bf16x8*)(svw+base);
    bf16x8 v2 = *(const bf16x8*)(svew+base);
    #pragma unroll
    for(int e=0;e<8;e++){
      s1l[w][hc*8+e] = s2f(v1[e]);
      s2l[w][hc*8+e] = s2f(v2[e]);
    }
  }
  int ch0 = g*64+2*c;
  float a1=fws[F_OA+ch0], b1=fws[F_OB+ch0], a2=fws[F_OA+ch0+1], b2=fws[F_OB+ch0+1];
  __syncthreads();
  size_t obase = (size_t)(n*CCH+oc)*SSP;
  for(int idx=t; idx<784; idx+=256){
    int h = idx/14, w4 = (idx-h*14)*4;
    float4 o4;
    o4.x = a1*s1l[w4+0][h]+b1 + a2*s2l[w4+0][h]+b2;
    o4.y = a1*s1l[w4+1][h]+b1 + a2*s2l[w4+1][h]+b2;
    o4.z = a1*s1l[w4+2][h]+b1 + a2*s2l[w4+2][h]+b2;
    o4.w = a1*s1l[w4+3][h]+b1 + a2*s2l[w4+3][h]+b2;
    *reinterpret_cast<float4*>(out + obase + (size_t)h*WW + w4) = o4;
  }
}

extern "C" void kernel_launch(void* const* d_in, const int* in_sizes, int n_in,
                              void* d_out, int out_size, void* d_ws, size_t ws_size,
                              hipStream_t stream) {
  const float* x    = (const float*)d_in[0];
  const float* xd   = (const float*)d_in[1];
  const float* carw = (const float*)d_in[2];
  const float* carb = (const float*)d_in[3];
  const float* cadw = (const float*)d_in[4];
  const float* cadb = (const float*)d_in[5];
  const float* qw   = (const float*)d_in[6];
  const float* kw   = (const float*)d_in[7];
  const float* vw   = (const float*)d_in[8];
  const float* bnqg = (const float*)d_in[9];
  const float* bnqb = (const float*)d_in[10];
  const float* bnkg = (const float*)d_in[11];
  const float* bnkb = (const float*)d_in[12];
  const float* bnvg = (const float*)d_in[13];
  const float* bnvb = (const float*)d_in[14];
  const float* bnsg = (const float*)d_in[15];
  const float* bnsb = (const float*)d_in[16];
  const float* bnog = (const float*)d_in[17];
  const float* bnob = (const float*)d_in[18];
  const float* rel  = (const float*)d_in[19];
  float* out = (float*)d_out;

  char* ws = (char*)d_ws;
  const size_t PROJ_BYTES = (size_t)NN*OCT*SSP*sizeof(bf16);
  const size_t XT_BYTES   = (size_t)NN*SSP*CCH*sizeof(bf16);
  const size_t WQS_BYTES  = (size_t)NN*128*256*sizeof(bf16);
  const size_t VWB_BYTES  = (size_t)256*256*sizeof(bf16);
  const size_t FWS_BYTES  = (size_t)F_TOT*sizeof(float);
  const size_t TB_BYTES   = (size_t)((T_TOT+7)/8*8)*sizeof(short);

  size_t off = 0;
  bf16* proj = (bf16*)(ws + off); off += PROJ_BYTES;
  bf16* xT   = (bf16*)(ws + off); size_t off_xT = off; off += XT_BYTES;
  bf16* xdT  = (bf16*)(ws + off); size_t off_xdT = off; off += XT_BYTES;
  bf16* xfT  = (bf16*)(ws + off); off += XT_BYTES;
  bf16* wqs  = (bf16*)(ws + off); off += WQS_BYTES;
  bf16* wks  = (bf16*)(ws + off); off += WQS_BYTES;
  bf16* vwb  = (bf16*)(ws + off); off += VWB_BYTES;
  float* fws = (float*)(ws + off); off += FWS_BYTES;
  short* tb  = (short*)(ws + off); off += TB_BYTES;
  if (ws_size < off) return;
  bf16* svw  = (bf16*)(ws + off_xT);
  bf16* svew = (bf16*)(ws + off_xdT);

  hipMemsetAsync(fws, 0, (size_t)F_ACC_END*sizeof(float), stream);
  k_prep<<<dim3(98,NN), 256, 0, stream>>>(x, xd, rel, fws, tb, xT, xdT, xfT);
  k_chanatt<<<NN, 256, 0, stream>>>(carw, carb, cadw, cadb, fws);
  k_wprep<<<17, 256, 0, stream>>>(qw, kw, vw, fws, wqs, wks, vwb);
  k_gemm<<<dim3(3136), 256, 0, stream>>>(xT, xdT, xfT, wqs, wks, vwb, fws, proj);
  k_finproj<<<1, 512, 0, stream>>>(bnqg,bnqb,bnkg,bnkb,bnvg,bnvb, fws);
  k_simstat<<<dim3(8,NN,GG), 256, 0, stream>>>(proj, tb, fws);
  k_finsim<<<1, 32, 0, stream>>>(bnsg, bnsb, fws);
  k_att<<<dim3(GG,WW,NN), 512, 0, stream>>>(proj, tb, fws, svw, svew);
  k_finout<<<1, 512, 0, stream>>>(bnog, bnob, fws);
  k_out<<<dim3(CCH,NN), 256, 0, stream>>>(svw, svew, fws, out);
}

// Round 15
// 428.046 us; speedup vs baseline: 5.3680x; 1.0038x over previous
//
#include <hip/hip_runtime.h>
#include <hip/hip_bf16.h>
#include <math.h>

typedef __hip_bfloat16 bf16;
typedef __attribute__((ext_vector_type(8))) short bf16x8;
typedef __attribute__((ext_vector_type(4))) float f32x4;

#define NN 16
#define CCH 256
#define HH 56
#define WW 56
#define SSP 3136
#define GG 8
#define GPH 16
#define GPF 32
#define OCT 512
#define RL 111
#define EPSV 1e-5f
#define CNT_PROJ 50176.0f
#define CNT_SIM  2809856.0f

__device__ __forceinline__ float bf2f(bf16 v){ return __bfloat162float(v); }
__device__ __forceinline__ bf16 f2bf(float v){ return __float2bfloat16(v); }
__device__ __forceinline__ short f2s(float f){ bf16 h = __float2bfloat16(f); return __builtin_bit_cast(short, h); }
__device__ __forceinline__ float s2f(short s){ bf16 h = __builtin_bit_cast(bf16, s); return __bfloat162float(h); }
__device__ __forceinline__ unsigned pk2(float a, float b){
  return (unsigned)(unsigned short)f2s(a) | ((unsigned)(unsigned short)f2s(b)<<16);
}

__device__ __forceinline__ void gl16(const void* g, void* l){
  __builtin_amdgcn_global_load_lds((const __attribute__((address_space(1))) void*)g,
                                   (__attribute__((address_space(3))) void*)l, 16, 0, 0);
}

// ---- f32 workspace region layout (float indices) ----
#define F_PR 0
#define F_PD 4096
#define F_SR 8192
#define F_SD 12288
#define F_PSUM 16384
#define F_PSQ  16896
#define F_PA   17408
#define F_PB   17920
#define F_SSUM 18432
#define F_SSQ  18464
#define F_SA   18496
#define F_SB   18528
#define F_OSUM 18560
#define F_OSQ  19072
#define F_OA   19584
#define F_OB   20096
#define F_ACC_END 20608
#define F_TOT  20608
// bf16 table region (shorts)
#define T_RQ 0        // [112][24]
#define T_RK 2688     // [112][24]
#define T_RV 5376     // [32][128]
#define T_TOT 9472

// k_att LDS layout (bytes)
#define STQ 24
#define SQT 58
#define STA 72
#define STSH 136
#define STG 72
#define OFF_QA   0
#define OFF_KA   3072
#define OFF_QR   6144
#define OFF_KR   19136
#define OFF_VB   32128
#define OFF_FAC  36736
#define OFF_OST  36992
#define SMSZ     37504
#define OFF_SIMA 0
#define OFF_SIMSH 9216
#define ZERO_I4  1664

// k_simstat LDS (shorts per buffer)
#define SB_QA 0
#define SB_KA 1536
#define SB_QG 3072
#define SB_KG 4224
#define SB_TOT 5376
#define SB_ZI4 1344

// ============ K1: prep (+ tables in block (0,0)) ============
__global__ __launch_bounds__(256) void k_prep(const float* __restrict__ x, const float* __restrict__ xd,
                                              const float* __restrict__ rel,
                                              float* __restrict__ fws, short* __restrict__ tb,
                                              bf16* __restrict__ xT, bf16* __restrict__ xdT, bf16* __restrict__ xfT){
  __shared__ __align__(16) short tx[32*264];
  __shared__ __align__(16) short td[32*264];
  __shared__ __align__(16) short tf[32*264];
  int s0 = blockIdx.x*32, n = blockIdx.y;
  int t = threadIdx.x;
  int si = t & 31, cg = t >> 5;
  for(int cc=0; cc<CCH; cc+=8){
    int c = cc + cg;
    size_t gi = ((size_t)n*CCH + c)*SSP + s0 + si;
    float vx = x[gi], vd = xd[gi];
    tx[si*264+c] = f2s(vx);
    td[si*264+c] = f2s(vd);
    tf[si*264+c] = f2s(vx*vd);
  }
  __syncthreads();
  {
    float s1=0.f, s2=0.f;
    for(int sr=0; sr<32; sr++){ s1 += s2f(tx[sr*264+t]); s2 += s2f(td[sr*264+t]); }
    atomicAdd(&fws[F_PR+n*CCH+t], s1);
    atomicAdd(&fws[F_PD+n*CCH+t], s2);
  }
  size_t rbase = (size_t)n*SSP;
  for(int idx=t; idx<32*32; idx+=256){
    int sr2 = idx>>5, ch = idx&31;
    int sp = s0 + sr2;
    int s2 = (sp%WW)*HH + sp/WW;
    float4 v1 = *(const float4*)(tx + sr2*264 + ch*8);
    float4 v2 = *(const float4*)(td + sr2*264 + ch*8);
    float4 v3 = *(const float4*)(tf + sr2*264 + ch*8);
    *reinterpret_cast<float4*>(xT  + (rbase + s2)*CCH + ch*8) = v1;
    *reinterpret_cast<float4*>(xdT + (rbase + s2)*CCH + ch*8) = v2;
    *reinterpret_cast<float4*>(xfT + (rbase + s2)*CCH + ch*8) = v3;
  }
  if(blockIdx.x==0 && blockIdx.y==0){
    for(int idx=t; idx<112*24; idx+=256){
      int d = idx/24, c = idx - d*24;
      short vq=0, vk=0;
      if(c<16 && d<RL){ vq = f2s(rel[c*RL+d]); vk = f2s(rel[(16+c)*RL+d]); }
      tb[T_RQ+idx]=vq; tb[T_RK+idx]=vk;
    }
    for(int idx=t; idx<32*128; idx+=256){
      int c = idx>>7, d = idx&127;
      short v=0;
      if(d<RL) v = f2s(rel[(32+c)*RL+d]);
      tb[T_RV+idx]=v;
    }
  }
}

// ============ K2: channel attention scales ============
__global__ __launch_bounds__(256) void k_chanatt(const float* __restrict__ wr, const float* __restrict__ br,
                                                 const float* __restrict__ wd, const float* __restrict__ bd,
                                                 float* __restrict__ fws){
  int c = threadIdx.x, n = blockIdx.x;
  __shared__ float red[256];
  __shared__ float prl[256], pdl[256];
  prl[c]=fws[F_PR+n*CCH+c]*(1.f/SSP); pdl[c]=fws[F_PD+n*CCH+c]*(1.f/SSP);
  __syncthreads();
  float dr=br[c], dd=bd[c];
  for(int k=0;k<CCH;k++){ dr = fmaf(prl[k], wr[c*CCH+k], dr); dd = fmaf(pdl[k], wd[c*CCH+k], dd); }
  dr = fmaxf(dr,0.f); dd = fmaxf(dd,0.f);
  float car = 1.f/(1.f+expf(-dr));
  float cad = 1.f/(1.f+expf(-dd));
  float tv = car+cad;
  red[c]=tv; __syncthreads();
  for(int st=128;st>0;st>>=1){ if(c<st) red[c]=fmaxf(red[c],red[c+st]); __syncthreads(); }
  float mx = red[0]; __syncthreads();
  float e = expf(tv-mx);
  red[c]=e; __syncthreads();
  for(int st=128;st>0;st>>=1){ if(c<st) red[c]+=red[c+st]; __syncthreads(); }
  float co = e/red[0];
  fws[F_SR+n*CCH+c] = co+car;
  fws[F_SD+n*CCH+c] = co+cad;
}

// ============ K3: weight prep ============
__global__ __launch_bounds__(256) void k_wprep(const float* __restrict__ qw, const float* __restrict__ kw,
                                               const float* __restrict__ vw, const float* __restrict__ fws,
                                               bf16* __restrict__ wqs, bf16* __restrict__ wks, bf16* __restrict__ vwb){
  int b = blockIdx.x, t = threadIdx.x;
  if(b<16){
    const float* sr = fws + F_SR + b*CCH;
    const float* sd = fws + F_SD + b*CCH;
    for(int idx=t; idx<128*256; idx+=256){
      int c = idx & 255;
      wqs[b*32768+idx] = f2bf(qw[idx]*sr[c]);
      wks[b*32768+idx] = f2bf(kw[idx]*sd[c]);
    }
  } else {
    for(int idx=t; idx<256*256; idx+=256) vwb[idx] = f2bf(vw[idx]);
  }
}

// ============ K4: MFMA projection GEMM — 64s x 128o tiles ============
__global__ __launch_bounds__(256) void k_gemm(const bf16* __restrict__ xT, const bf16* __restrict__ xdT,
                                              const bf16* __restrict__ xfT,
                                              const bf16* __restrict__ wqs, const bf16* __restrict__ wks,
                                              const bf16* __restrict__ vwb,
                                              float* __restrict__ fws, bf16* __restrict__ proj){
  __shared__ __align__(16) char sm[50176];
  int bid = blockIdx.x;
  int sw = (bid & 7)*392 + (bid >> 3);
  int p = sw & 3;
  int rest = sw >> 2;
  int s_t = rest % 49;
  int n   = rest / 49;
  int s0g = s_t*64;

  const bf16* Ag = (p==0 ? xT : (p==1 ? xdT : xfT)) + (size_t)n*SSP*CCH;
  const bf16* Wg = (p==0) ? (wqs + (size_t)n*32768)
                 : (p==1) ? (wks + (size_t)n*32768)
                          : (vwb + (size_t)(p-2)*128*256);

  int tid = threadIdx.x;
  int w = tid>>6, lane = tid&63;
  int l15 = lane & 15, l4 = lane >> 4;

  float* sst = (float*)(sm + 49152);
  sst[tid]=0.f;

  f32x4 acc[2][4];
  #pragma unroll
  for(int f=0;f<2;f++)
    #pragma unroll
    for(int e=0;e<4;e++) acc[f][e]=(f32x4){0,0,0,0};

  auto stage = [&](int b, int kk){
    #pragma unroll
    for(int j=0;j<2;j++){
      int rowstart = w*16 + j*8;
      int row = rowstart + (lane>>3);
      int ch  = (lane&7) ^ (row&7);
      gl16(Ag + (size_t)(s0g + row)*CCH + kk*64 + ch*8, sm + (b?8192:0) + rowstart*128);
    }
    #pragma unroll
    for(int j=0;j<4;j++){
      int rowstart = w*32 + j*8;
      int row = rowstart + (lane>>3);
      int ch  = (lane&7) ^ (row&7);
      gl16(Wg + (size_t)row*CCH + kk*64 + ch*8, sm + 16384 + (b?16384:0) + rowstart*128);
    }
  };

  stage(0,0);
  __syncthreads();
  int cur=0;
  int sl0 = (w&1)*32, ol0 = (w>>1)*64;
  for(int kk=0;kk<4;kk++){
    if(kk<3) stage(cur^1, kk+1);
    const short* Ab = (const short*)(sm + (cur?8192:0));
    const short* Bb = (const short*)(sm + 16384 + (cur?16384:0));
    #pragma unroll
    for(int kh=0;kh<2;kh++){
      bf16x8 a[2], b[4];
      #pragma unroll
      for(int f=0;f<2;f++){
        int sr = sl0 + f*16 + l15;
        int chv = (kh*4 + l4) ^ (sr&7);
        a[f] = *(const bf16x8*)(Ab + sr*64 + chv*8);
      }
      #pragma unroll
      for(int e=0;e<4;e++){
        int orw = ol0 + e*16 + l15;
        int chv = (kh*4 + l4) ^ (orw&7);
        b[e] = *(const bf16x8*)(Bb + orw*64 + chv*8);
      }
      #pragma unroll
      for(int f=0;f<2;f++)
        #pragma unroll
        for(int e=0;e<4;e++)
          acc[f][e] = __builtin_amdgcn_mfma_f32_16x16x32_bf16(a[f], b[e], acc[f][e], 0,0,0);
    }
    __syncthreads();
    cur ^= 1;
  }

  #pragma unroll
  for(int e=0;e<4;e++){
    float s1=0.f, s2=0.f;
    #pragma unroll
    for(int f=0;f<2;f++)
      #pragma unroll
      for(int r=0;r<4;r++){ float v=acc[f][e][r]; s1+=v; s2+=v*v; }
    s1 += __shfl_xor(s1,16); s2 += __shfl_xor(s2,16);
    s1 += __shfl_xor(s1,32); s2 += __shfl_xor(s2,32);
    if(l4==0){
      int ol = ol0 + e*16 + l15;
      atomicAdd(&sst[ol], s1);
      atomicAdd(&sst[128+ol], s2);
    }
  }
  #pragma unroll
  for(int f=0;f<2;f++)
    #pragma unroll
    for(int e=0;e<4;e++){
      int sbase = s0g + (w&1)*32 + f*16 + l4*4;
      int o = p*128 + ol0 + e*16 + l15;
      short4 pk;
      pk.x = f2s(acc[f][e][0]); pk.y = f2s(acc[f][e][1]);
      pk.z = f2s(acc[f][e][2]); pk.w = f2s(acc[f][e][3]);
      *reinterpret_cast<short4*>(proj + ((size_t)n*OCT + o)*SSP + sbase) = pk;
    }
  __syncthreads();
  if(tid<128){
    int og = p*128 + tid;
    atomicAdd(&fws[F_PSUM+og], sst[tid]);
    atomicAdd(&fws[F_PSQ+og],  sst[128+tid]);
  }
}

// ============ K5: finalize proj BN ============
__global__ void k_finproj(const float* qg,const float* qb,const float* kg,const float* kb,
                          const float* vg,const float* vb, float* fws){
  int o = threadIdx.x;
  float m = fws[F_PSUM+o]*(1.0f/CNT_PROJ);
  float var = fws[F_PSQ+o]*(1.0f/CNT_PROJ) - m*m;
  float g,b;
  if(o<128){ g=qg[o]; b=qb[o]; }
  else if(o<256){ g=kg[o-128]; b=kb[o-128]; }
  else { g=vg[o-256]; b=vb[o-256]; }
  float a = g*rsqrtf(var+EPSV);
  fws[F_PA+o]=a; fws[F_PB+o]=b-m*a;
}

// ============ K6: sim-BN stats — 7 w per block, band-pruned tiles ============
__global__ __launch_bounds__(256) void k_simstat(const bf16* __restrict__ proj,
                                                 const short* __restrict__ tb,
                                                 float* __restrict__ fws){
  __shared__ __align__(16) short smS[2*SB_TOT];
  __shared__ float redW[4][4];
  __shared__ float red2[2];
  int wq = blockIdx.x, n = blockIdx.y, g = blockIdx.z;
  int t = threadIdx.x;
  int W = t>>6, lane = t&63;
  int l15 = lane&15, l4 = lane>>4;
  const short* rqB = tb + T_RQ;
  const short* rkB = tb + T_RK;
  const bf16x8 z8 = {};

  for(int i=t; i<SB_ZI4; i+=256) ((int4*)smS)[i] = (int4){0,0,0,0};

  int isLoader = (t<224);
  int rid = t/7, ch = t - rid*7;
  int isK = rid>=16, c = rid&15;
  int o = (isK?128:0) + g*GPH + c;
  float pa=0.f, pb=0.f;
  const bf16* gsrc = proj + ((size_t)n*OCT+o)*SSP + ch*8;
  if(isLoader){ pa = fws[F_PA+o]; pb = fws[F_PB+o]; }
  int w0 = wq*7;

  auto stageWrite = [&](short* buf, bf16x8 vv){
    bf16x8 rv;
    #pragma unroll
    for(int e=0;e<8;e++) rv[e] = f2s(pa*s2f(vv[e])+pb);
    short* dA = buf + (isK? SB_KA : SB_QA);
    #pragma unroll
    for(int e=0;e<8;e++) dA[(ch*8+e)*STQ + c] = rv[e];
    short* gRow = buf + (isK? SB_KG : SB_QG) + c*STG;
    *(bf16x8*)(gRow + ch*8) = rv;
  };

  bf16x8 ld = z8;
  if(isLoader) ld = *(const bf16x8*)(gsrc + (size_t)w0*HH);
  __syncthreads();
  if(isLoader) stageWrite(smS, ld);
  __syncthreads();

  float sQ=0.f,qQ=0.f,sK=0.f,qK=0.f,pSS=0.f,pS=0.f;
  #pragma unroll 1
  for(int it=0; it<7; it++){
    bf16x8 nx = z8;
    if(it<6 && isLoader) nx = *(const bf16x8*)(gsrc + (size_t)(w0+it+1)*HH);
    const short* buf = smS + (it&1)*SB_TOT;
    const short* qA = buf + SB_QA;
    const short* kA = buf + SB_KA;
    const short* qG = buf + SB_QG;
    const short* kG = buf + SB_KG;

    // band-pruned tiles: 19 per matrix (-15 <= d0-i0 <= 70)
    for(int T=W; T<38; T+=4){
      int tk = (T>=19);
      int t2 = tk ? T-19 : T;
      int ti = t2/5;
      int td = t2 - 4*ti;
      int i0 = ti*16, d0 = td*16;
      const short* aBase = tk ? kA : qA;
      const short* bBase = tk ? rkB : rqB;
      bf16x8 av = (l4<2)? *(const bf16x8*)(aBase + (i0+l15)*STQ + l4*8) : z8;
      bf16x8 bv = (l4<2)? *(const bf16x8*)(bBase + (d0+l15)*24 + l4*8) : z8;
      f32x4 acc = {0.f,0.f,0.f,0.f};
      acc = __builtin_amdgcn_mfma_f32_16x16x32_bf16(av, bv, acc, 0,0,0);
      int d = d0 + l15;
      #pragma unroll
      for(int r=0;r<4;r++){
        int i = i0 + l4*4 + r;
        int dmi = d - i;
        if(dmi>=0 && dmi<56){
          float v = acc[r];
          if(tk){ sK += v; qK += v*v; }
          else  { sQ += v; qQ += v*v; }
        }
      }
    }
    if(W==0){
      bf16x8 a0 = *(const bf16x8*)(qG + l15*STG + l4*8);
      bf16x8 a1 = *(const bf16x8*)(qG + l15*STG + 32 + l4*8);
      f32x4 gq = {0.f,0.f,0.f,0.f};
      gq = __builtin_amdgcn_mfma_f32_16x16x32_bf16(a0, a0, gq, 0,0,0);
      gq = __builtin_amdgcn_mfma_f32_16x16x32_bf16(a1, a1, gq, 0,0,0);
      bf16x8 b0 = *(const bf16x8*)(kG + l15*STG + l4*8);
      bf16x8 b1 = *(const bf16x8*)(kG + l15*STG + 32 + l4*8);
      f32x4 gk = {0.f,0.f,0.f,0.f};
      gk = __builtin_amdgcn_mfma_f32_16x16x32_bf16(b0, b0, gk, 0,0,0);
      gk = __builtin_amdgcn_mfma_f32_16x16x32_bf16(b1, b1, gk, 0,0,0);
      pSS += gq[0]*gk[0]+gq[1]*gk[1]+gq[2]*gk[2]+gq[3]*gk[3];
    } else if(W==1){
      float rsum = 0.f;
      if(lane<32){
        const short* row = (lane<16)? (qG + lane*STG) : (kG + (lane-16)*STG);
        #pragma unroll
        for(int i8=0;i8<7;i8++){
          bf16x8 v8 = *(const bf16x8*)(row + i8*8);
          #pragma unroll
          for(int e=0;e<8;e++) rsum += s2f(v8[e]);
        }
      }
      float kv = __shfl(rsum, (lane+16)&63);
      if(lane<16) pS += rsum*kv;
    }

    if(it<6){
      __syncthreads();
      if(isLoader) stageWrite(smS + ((it+1)&1)*SB_TOT, nx);
      __syncthreads();
    }
  }

  float b4[4] = {sQ,qQ,sK,qK};
  #pragma unroll
  for(int u=0;u<4;u++){
    float v = b4[u];
    #pragma unroll
    for(int msk=1;msk<64;msk<<=1) v += __shfl_xor(v,msk);
    if(lane==0) redW[W][u] = v;
  }
  if(W==0){
    float p = pSS;
    #pragma unroll
    for(int msk=1;msk<64;msk<<=1) p += __shfl_xor(p,msk);
    if(lane==0) red2[1] = p;
  } else if(W==1){
    float p = (lane<16)? pS : 0.f;
    #pragma unroll
    for(int msk=1;msk<16;msk<<=1) p += __shfl_xor(p,msk);
    if(lane==0) red2[0] = p;
  }
  __syncthreads();
  if(t<4){
    float s = redW[0][t]+redW[1][t]+redW[2][t]+redW[3][t];
    int tgt = (t==0)? (F_SSUM+8+g) : (t==1)? (F_SSQ+8+g) : (t==2)? (F_SSUM+16+g) : (F_SSQ+16+g);
    atomicAdd(&fws[tgt], s);
  } else if(t==4){
    atomicAdd(&fws[F_SSUM+g], red2[0]);
  } else if(t==5){
    atomicAdd(&fws[F_SSQ+g], red2[1]);
  }
}

__global__ void k_finsim(const float* sg, const float* sb, float* fws){
  int ch = threadIdx.x; if(ch>=24) return;
  float m = fws[F_SSUM+ch]*(1.0f/CNT_SIM);
  float var = fws[F_SSQ+ch]*(1.0f/CNT_SIM) - m*m;
  float a = sg[ch]*rsqrtf(var+EPSV);
  fws[F_SA+ch]=a; fws[F_SB+ch]=sb[ch]-m*a;
}

// ============ K7: main MFMA attention — 2 w per block, prefetch, band-pruned P2a ============
__global__ __launch_bounds__(512) void k_att(const bf16* __restrict__ proj,
                                             const short* __restrict__ tb,
                                             float* __restrict__ fws,
                                             bf16* __restrict__ svw, bf16* __restrict__ svew){
  __shared__ __align__(16) char sm[SMSZ];
  int g = blockIdx.x, wq = blockIdx.y, n = blockIdx.z;
  int tid = threadIdx.x;
  int W = tid >> 6, lane = tid & 63;
  int l15 = lane & 15, l4 = lane >> 4;
  short* qA = (short*)(sm + OFF_QA);
  short* kA = (short*)(sm + OFF_KA);
  short* qrT = (short*)(sm + OFF_QR);
  short* krT = (short*)(sm + OFF_KR);
  short* vB  = (short*)(sm + OFF_VB);
  float* rfacL = (float*)(sm + OFF_FAC);
  const short* rqB = tb + T_RQ;
  const short* rkB = tb + T_RK;
  const short* rvBg = tb + T_RV;
  const float* PA = fws + F_PA;
  const float* PB = fws + F_PB;
  const bf16x8 z8 = {};

  float aqk = fws[F_SA+g], aqr = fws[F_SA+8+g], akr = fws[F_SA+16+g];
  float bsum = fws[F_SB+g]+fws[F_SB+8+g]+fws[F_SB+16+g];

  if(tid<128) ((float*)(sm+OFF_OST))[tid]=0.f;

  // loader setup
  int rid = tid/7, ch = tid - rid*7;
  int o=0, c=0, isV=0;
  float pa=0.f, pb=0.f;
  const bf16* src0 = proj;
  if(tid<448){
    if(rid<16){ c=rid; o = g*GPH + c; }
    else if(rid<32){ c=rid-16; o = 128 + g*GPH + c; }
    else { c=rid-32; o = 256 + g*GPF + c; isV=1; }
    pa = PA[o]; pb = PB[o];
    src0 = proj + ((size_t)n*OCT + o)*SSP + (2*wq)*HH + ch*8;
  }

  auto stageW = [&](bf16x8 vv){
    if(tid<448){
      bf16x8 rv;
      #pragma unroll
      for(int e=0;e<8;e++) rv[e] = f2s(pa*s2f(vv[e])+pb);
      if(!isV){
        short* dst = (rid<16)? qA : kA;
        #pragma unroll
        for(int e=0;e<8;e++) dst[(ch*8+e)*STQ + c] = rv[e];
      } else {
        *(bf16x8*)(vB + c*STA + ch*8) = rv;
        if(ch==0){
          *(bf16x8*)(vB + c*STA + 56) = z8;
          *(bf16x8*)(vB + c*STA + 64) = z8;
        }
      }
    } else {
      int z = tid-448;
      if(z<48){
        short* arr = (z<24)? qA : kA;
        int zz = (z<24)? z : z-24;
        *(int4*)((char*)arr + 56*STQ*2 + zz*16) = (int4){0,0,0,0};
      }
    }
  };

  bf16x8 vv0 = z8;
  if(tid<448) vv0 = *(const bf16x8*)src0;
  stageW(vv0);
  __syncthreads();

  short* simA = (short*)(sm + OFF_SIMA);
  short* simSh = (short*)(sm + OFF_SIMSH);
  float* ostS = (float*)(sm + OFF_OST);
  float* ostQ = ostS + 64;

  for(int it=0; it<2; it++){
    int w = 2*wq + it;
    bf16x8 vnx = z8;
    if(it==0 && tid<448) vnx = *(const bf16x8*)(src0 + HH);   // prefetch next w

    // P2a: band-pruned QR/KR tiles (19 each)
    for(int T=W; T<38; T+=8){
      int isK = (T>=19);
      int t2 = isK ? T-19 : T;
      int ti = t2/5;
      int td = t2 - 4*ti;
      int i0 = ti*16, d0 = td*16;
      const short* aBase = isK ? kA : qA;
      const short* bBase = isK ? rkB : rqB;
      bf16x8 av = (l4<2)? *(const bf16x8*)(aBase + (i0+l15)*STQ + l4*8) : z8;
      bf16x8 bv = (l4<2)? *(const bf16x8*)(bBase + (d0+l15)*24 + l4*8) : z8;
      f32x4 acc = {0.f,0.f,0.f,0.f};
      acc = __builtin_amdgcn_mfma_f32_16x16x32_bf16(av, bv, acc, 0,0,0);
      short* dst = isK ? krT : qrT;
      int d = d0 + l15;
      int ib = i0 + l4*4;
      if(ib < 53){
        unsigned* wp = (unsigned*)(dst + d*SQT + ib);
        wp[0] = pk2(acc[0], acc[1]);
        wp[1] = pk2(acc[2], acc[3]);
      }
    }
    __syncthreads();

    // P2b: QK tiles + skew-gather; e = exp(v)
    float e8[8];
    #pragma unroll
    for(int tt=0; tt<2; tt++){
      int T = W + 8*tt;
      int ti = T>>2, tj = T&3;
      int i0 = ti*16, j0 = tj*16;
      bf16x8 av = (l4<2)? *(const bf16x8*)(qA + (i0+l15)*STQ + l4*8) : z8;
      bf16x8 bv = (l4<2)? *(const bf16x8*)(kA + (j0+l15)*STQ + l4*8) : z8;
      f32x4 acc = {0.f,0.f,0.f,0.f};
      acc = __builtin_amdgcn_mfma_f32_16x16x32_bf16(av, bv, acc, 0,0,0);
      int j = j0 + l15;
      int jv = (j < HH);
      #pragma unroll
      for(int r=0;r<4;r++){
        int i = i0 + l4*4 + r;
        float vqr = s2f(qrT[(i-j+55)*SQT + i]);
        float vkr = s2f(krT[(j-i+55)*SQT + j]);
        float v = aqk*acc[r] + aqr*vqr + akr*vkr + bsum;
        e8[tt*4+r] = jv ? __expf(v) : 0.f;
      }
    }
    __syncthreads();

    // zero sim region
    for(int idx=tid; idx<ZERO_I4; idx+=512) ((int4*)sm)[idx] = (int4){0,0,0,0};
    __syncthreads();

    // scatter unnormalized e
    #pragma unroll
    for(int tt=0; tt<2; tt++){
      int T = W + 8*tt;
      int ti = T>>2, tj = T&3;
      int j = tj*16 + l15;
      #pragma unroll
      for(int r=0;r<4;r++){
        int i = ti*16 + l4*4 + r;
        if(i<HH && j<HH){
          short pv = f2s(e8[tt*4+r]);
          simA[i*STA + j] = pv;
          simSh[i*STSH + (i+55-j)] = pv;
        }
      }
    }
    __syncthreads();

    // P4a: row sums via MFMA ones-trick (waves 4-7)
    if(W>=4){
      int i0 = (W-4)*16;
      const short one_s = 0x3F80;
      bf16x8 onesv = {one_s,one_s,one_s,one_s,one_s,one_s,one_s,one_s};
      bf16x8 bv = (l15==0)? onesv : z8;
      f32x4 acc = {0.f,0.f,0.f,0.f};
      #pragma unroll
      for(int ks=0; ks<2; ks++){
        bf16x8 av = *(const bf16x8*)(simA + (i0+l15)*STA + ks*32 + l4*8);
        acc = __builtin_amdgcn_mfma_f32_16x16x32_bf16(av, bv, acc, 0,0,0);
      }
      if(l15==0){
        #pragma unroll
        for(int r=0;r<4;r++){
          int i = i0 + l4*4 + r;
          if(i<HH) rfacL[i] = 1.0f/acc[r];
        }
      }
    }

    // P4b: SV/SVE MFMA accumulators
    f32x4 accJ[2];
    #pragma unroll
    for(int jt=0; jt<2; jt++){
      int T = W + 8*jt;
      int isE = (T>=8);
      int tt = T&7;
      int ti = tt>>1, tc = tt&1;
      int i0 = ti*16, c0 = tc*16;
      f32x4 acc = {0.f,0.f,0.f,0.f};
      if(!isE){
        #pragma unroll
        for(int ks=0; ks<2; ks++){
          int j0 = ks*32;
          bf16x8 av = *(const bf16x8*)(simA + (i0+l15)*STA + j0 + l4*8);
          bf16x8 bv = *(const bf16x8*)(vB + (c0+l15)*STA + j0 + l4*8);
          acc = __builtin_amdgcn_mfma_f32_16x16x32_bf16(av, bv, acc, 0,0,0);
        }
      } else {
        #pragma unroll
        for(int ks=0; ks<4; ks++){
          int d0 = ks*32;
          bf16x8 av = *(const bf16x8*)(simSh + (i0+l15)*STSH + d0 + l4*8);
          bf16x8 bv = *(const bf16x8*)(rvBg + (c0+l15)*128 + d0 + l4*8);
          acc = __builtin_amdgcn_mfma_f32_16x16x32_bf16(av, bv, acc, 0,0,0);
        }
      }
      accJ[jt] = acc;
    }
    __syncthreads();   // rfacL ready; simA/simSh dead

    // P5: epilogue (+ stage next w into qA/kA/vB — aliases dead simA)
    #pragma unroll
    for(int jt=0; jt<2; jt++){
      int T = W + 8*jt;
      int isE = (T>=8);
      int tt = T&7;
      int ti = tt>>1, tc = tt&1;
      int i0 = ti*16, c0 = tc*16;
      f32x4 acc = accJ[jt];
      int cc = c0 + l15;
      int ib = i0 + l4*4;
      float s1=0.f, s2=0.f;
      if(ib+3 < HH){
        float4 rf = *(const float4*)(rfacL + ib);
        acc[0]*=rf.x; acc[1]*=rf.y; acc[2]*=rf.z; acc[3]*=rf.w;
        size_t gb = ((((size_t)n*WW + w)*GG + g)*GPF + cc)*HH;
        bf16* dst = isE ? svew : svw;
        short4 pk;
        pk.x = f2s(acc[0]); pk.y = f2s(acc[1]); pk.z = f2s(acc[2]); pk.w = f2s(acc[3]);
        *reinterpret_cast<short4*>(dst + gb + ib) = pk;
        #pragma unroll
        for(int r=0;r<4;r++){ s1 += acc[r]; s2 += acc[r]*acc[r]; }
      }
      int u = 2*cc + (isE?1:0);
      atomicAdd(&ostS[u], s1);
      atomicAdd(&ostQ[u], s2);
    }
    if(it==0) stageW(vnx);
    __syncthreads();
  }

  if(tid<64){
    atomicAdd(&fws[F_OSUM + g*64 + tid], ostS[tid]);
    atomicAdd(&fws[F_OSQ  + g*64 + tid], ostQ[tid]);
  }
}

__global__ void k_finout(const float* og, const float* ob, float* fws){
  int o = threadIdx.x;
  float m = fws[F_OSUM+o]*(1.0f/CNT_PROJ);
  float var = fws[F_OSQ+o]*(1.0f/CNT_PROJ) - m*m;
  float a = og[o]*rsqrtf(var+EPSV);
  fws[F_OA+o]=a; fws[F_OB+o]=ob[o]-m*a;
}

__global__ __launch_bounds__(256) void k_out(const bf16* __restrict__ svw, const bf16* __restrict__ svew,
                                             const float* __restrict__ fws, float* __restrict__ out){
  int oc = blockIdx.x, n = blockIdx.y;
  int g = oc>>5, c = oc&31;
  __shared__ float s1l[WW][57], s2l[WW][57];
  int t=threadIdx.x;
  for(int idx=t; idx<392; idx+=256){
    int w = idx/7, hc = idx-w*7;
    size_t base = (((size_t)(n*WW+w)*GG+g)*GPF+c)*HH + hc*8;
    bf16x8 v1 = *(const bf16x8*)(svw+base);
    bf16x8 v2 = *(const bf16x8*)(svew+base);
    #pragma unroll
    for(int e=0;e<8;e++){
      s1l[w][hc*8+e] = s2f(v1[e]);
      s2l[w][hc*8+e] = s2f(v2[e]);
    }
  }
  int ch0 = g*64+2*c;
  float a1=fws[F_OA+ch0], b1=fws[F_OB+ch0], a2=fws[F_OA+ch0+1], b2=fws[F_OB+ch0+1];
  __syncthreads();
  size_t obase = (size_t)(n*CCH+oc)*SSP;
  for(int idx=t; idx<784; idx+=256){
    int h = idx/14, w4 = (idx-h*14)*4;
    float4 o4;
    o4.x = a1*s1l[w4+0][h]+b1 + a2*s2l[w4+0][h]+b2;
    o4.y = a1*s1l[w4+1][h]+b1 + a2*s2l[w4+1][h]+b2;
    o4.z = a1*s1l[w4+2][h]+b1 + a2*s2l[w4+2][h]+b2;
    o4.w = a1*s1l[w4+3][h]+b1 + a2*s2l[w4+3][h]+b2;
    *reinterpret_cast<float4*>(out + obase + (size_t)h*WW + w4) = o4;
  }
}

extern "C" void kernel_launch(void* const* d_in, const int* in_sizes, int n_in,
                              void* d_out, int out_size, void* d_ws, size_t ws_size,
                              hipStream_t stream) {
  const float* x    = (const float*)d_in[0];
  const float* xd   = (const float*)d_in[1];
  const float* carw = (const float*)d_in[2];
  const float* carb = (const float*)d_in[3];
  const float* cadw = (const float*)d_in[4];
  const float* cadb = (const float*)d_in[5];
  const float* qw   = (const float*)d_in[6];
  const float* kw   = (const float*)d_in[7];
  const float* vw   = (const float*)d_in[8];
  const float* bnqg = (const float*)d_in[9];
  const float* bnqb = (const float*)d_in[10];
  const float* bnkg = (const float*)d_in[11];
  const float* bnkb = (const float*)d_in[12];
  const float* bnvg = (const float*)d_in[13];
  const float* bnvb = (const float*)d_in[14];
  const float* bnsg = (const float*)d_in[15];
  const float* bnsb = (const float*)d_in[16];
  const float* bnog = (const float*)d_in[17];
  const float* bnob = (const float*)d_in[18];
  const float* rel  = (const float*)d_in[19];
  float* out = (float*)d_out;

  char* ws = (char*)d_ws;
  const size_t PROJ_BYTES = (size_t)NN*OCT*SSP*sizeof(bf16);
  const size_t XT_BYTES   = (size_t)NN*SSP*CCH*sizeof(bf16);
  const size_t WQS_BYTES  = (size_t)NN*128*256*sizeof(bf16);
  const size_t VWB_BYTES  = (size_t)256*256*sizeof(bf16);
  const size_t FWS_BYTES  = (size_t)F_TOT*sizeof(float);
  const size_t TB_BYTES   = (size_t)((T_TOT+7)/8*8)*sizeof(short);

  size_t off = 0;
  bf16* proj = (bf16*)(ws + off); off += PROJ_BYTES;
  bf16* xT   = (bf16*)(ws + off); size_t off_xT = off; off += XT_BYTES;
  bf16* xdT  = (bf16*)(ws + off); size_t off_xdT = off; off += XT_BYTES;
  bf16* xfT  = (bf16*)(ws + off); off += XT_BYTES;
  bf16* wqs  = (bf16*)(ws + off); off += WQS_BYTES;
  bf16* wks  = (bf16*)(ws + off); off += WQS_BYTES;
  bf16* vwb  = (bf16*)(ws + off); off += VWB_BYTES;
  float* fws = (float*)(ws + off); off += FWS_BYTES;
  short* tb  = (short*)(ws + off); off += TB_BYTES;
  if (ws_size < off) return;
  bf16* svw  = (bf16*)(ws + off_xT);
  bf16* svew = (bf16*)(ws + off_xdT);

  hipMemsetAsync(fws, 0, (size_t)F_ACC_END*sizeof(float), stream);
  k_prep<<<dim3(98,NN), 256, 0, stream>>>(x, xd, rel, fws, tb, xT, xdT, xfT);
  k_chanatt<<<NN, 256, 0, stream>>>(carw, carb, cadw, cadb, fws);
  k_wprep<<<17, 256, 0, stream>>>(qw, kw, vw, fws, wqs, wks, vwb);
  k_gemm<<<dim3(3136), 256, 0, stream>>>(xT, xdT, xfT, wqs, wks, vwb, fws, proj);
  k_finproj<<<1, 512, 0, stream>>>(bnqg,bnqb,bnkg,bnkb,bnvg,bnvb, fws);
  k_simstat<<<dim3(8,NN,GG), 256, 0, stream>>>(proj, tb, fws);
  k_finsim<<<1, 32, 0, stream>>>(bnsg, bnsb, fws);
  k_att<<<dim3(GG,28,NN), 512, 0, stream>>>(proj, tb, fws, svw, svew);
  k_finout<<<1, 512, 0, stream>>>(bnog, bnob, fws);
  k_out<<<dim3(CCH,NN), 256, 0, stream>>>(svw, svew, fws, out);
}

// Round 16
// 414.056 us; speedup vs baseline: 5.5494x; 1.0338x over previous
//
#include <hip/hip_runtime.h>
#include <hip/hip_bf16.h>
#include <math.h>

typedef __hip_bfloat16 bf16;
typedef __attribute__((ext_vector_type(8))) short bf16x8;
typedef __attribute__((ext_vector_type(4))) float f32x4;

#define NN 16
#define CCH 256
#define HH 56
#define WW 56
#define SSP 3136
#define GG 8
#define GPH 16
#define GPF 32
#define OCT 512
#define RL 111
#define EPSV 1e-5f
#define CNT_PROJ 50176.0f
#define CNT_SIM  2809856.0f

__device__ __forceinline__ float bf2f(bf16 v){ return __bfloat162float(v); }
__device__ __forceinline__ bf16 f2bf(float v){ return __float2bfloat16(v); }
__device__ __forceinline__ short f2s(float f){ bf16 h = __float2bfloat16(f); return __builtin_bit_cast(short, h); }
__device__ __forceinline__ float s2f(short s){ bf16 h = __builtin_bit_cast(bf16, s); return __bfloat162float(h); }
__device__ __forceinline__ unsigned pk2(float a, float b){
  return (unsigned)(unsigned short)f2s(a) | ((unsigned)(unsigned short)f2s(b)<<16);
}

__device__ __forceinline__ void gl16(const void* g, void* l){
  __builtin_amdgcn_global_load_lds((const __attribute__((address_space(1))) void*)g,
                                   (__attribute__((address_space(3))) void*)l, 16, 0, 0);
}

// ---- f32 workspace region layout (float indices) ----
#define F_PR 0
#define F_PD 4096
#define F_SR 8192
#define F_SD 12288
#define F_PSUM 16384
#define F_PSQ  16896
#define F_PA   17408
#define F_PB   17920
#define F_SSUM 18432
#define F_SSQ  18464
#define F_SA   18496
#define F_SB   18528
#define F_OSUM 18560
#define F_OSQ  19072
#define F_OA   19584
#define F_OB   20096
#define F_ACC_END 20608
#define F_TOT  20608
// bf16 table region (shorts)
#define T_RQ 0        // [112][24]
#define T_RK 2688     // [112][24]
#define T_RV 5376     // [32][128]
#define T_TOT 9472

// k_att LDS layout (bytes)
#define STQ 24
#define SQT 58
#define STA 72
#define STSH 136
#define STG 72
#define OFF_QA   0
#define OFF_KA   3072
#define OFF_QR   6144
#define OFF_KR   19136
#define OFF_VB   32128
#define OFF_FAC  36736
#define OFF_OST  36992
#define SMSZ     37504
#define OFF_SIMA 0
#define OFF_SIMSH 9216
#define ZERO_I4  1664

// k_simstat LDS (shorts per buffer)
#define SB_QA 0
#define SB_KA 1536
#define SB_QG 3072
#define SB_KG 4224
#define SB_TOT 5376
#define SB_ZI4 1344

// ============ K1: prep (+ tables in block (0,0)) ============
__global__ __launch_bounds__(256) void k_prep(const float* __restrict__ x, const float* __restrict__ xd,
                                              const float* __restrict__ rel,
                                              float* __restrict__ fws, short* __restrict__ tb,
                                              bf16* __restrict__ xT, bf16* __restrict__ xdT, bf16* __restrict__ xfT){
  __shared__ __align__(16) short tx[32*264];
  __shared__ __align__(16) short td[32*264];
  __shared__ __align__(16) short tf[32*264];
  int s0 = blockIdx.x*32, n = blockIdx.y;
  int t = threadIdx.x;
  int si = t & 31, cg = t >> 5;
  for(int cc=0; cc<CCH; cc+=8){
    int c = cc + cg;
    size_t gi = ((size_t)n*CCH + c)*SSP + s0 + si;
    float vx = x[gi], vd = xd[gi];
    tx[si*264+c] = f2s(vx);
    td[si*264+c] = f2s(vd);
    tf[si*264+c] = f2s(vx*vd);
  }
  __syncthreads();
  {
    float s1=0.f, s2=0.f;
    for(int sr=0; sr<32; sr++){ s1 += s2f(tx[sr*264+t]); s2 += s2f(td[sr*264+t]); }
    atomicAdd(&fws[F_PR+n*CCH+t], s1);
    atomicAdd(&fws[F_PD+n*CCH+t], s2);
  }
  size_t rbase = (size_t)n*SSP;
  for(int idx=t; idx<32*32; idx+=256){
    int sr2 = idx>>5, ch = idx&31;
    int sp = s0 + sr2;
    int s2 = (sp%WW)*HH + sp/WW;
    float4 v1 = *(const float4*)(tx + sr2*264 + ch*8);
    float4 v2 = *(const float4*)(td + sr2*264 + ch*8);
    float4 v3 = *(const float4*)(tf + sr2*264 + ch*8);
    *reinterpret_cast<float4*>(xT  + (rbase + s2)*CCH + ch*8) = v1;
    *reinterpret_cast<float4*>(xdT + (rbase + s2)*CCH + ch*8) = v2;
    *reinterpret_cast<float4*>(xfT + (rbase + s2)*CCH + ch*8) = v3;
  }
  if(blockIdx.x==0 && blockIdx.y==0){
    for(int idx=t; idx<112*24; idx+=256){
      int d = idx/24, c = idx - d*24;
      short vq=0, vk=0;
      if(c<16 && d<RL){ vq = f2s(rel[c*RL+d]); vk = f2s(rel[(16+c)*RL+d]); }
      tb[T_RQ+idx]=vq; tb[T_RK+idx]=vk;
    }
    for(int idx=t; idx<32*128; idx+=256){
      int c = idx>>7, d = idx&127;
      short v=0;
      if(d<RL) v = f2s(rel[(32+c)*RL+d]);
      tb[T_RV+idx]=v;
    }
  }
}

// ============ K2: channel attention scales ============
__global__ __launch_bounds__(256) void k_chanatt(const float* __restrict__ wr, const float* __restrict__ br,
                                                 const float* __restrict__ wd, const float* __restrict__ bd,
                                                 float* __restrict__ fws){
  int c = threadIdx.x, n = blockIdx.x;
  __shared__ float red[256];
  __shared__ float prl[256], pdl[256];
  prl[c]=fws[F_PR+n*CCH+c]*(1.f/SSP); pdl[c]=fws[F_PD+n*CCH+c]*(1.f/SSP);
  __syncthreads();
  float dr=br[c], dd=bd[c];
  for(int k=0;k<CCH;k++){ dr = fmaf(prl[k], wr[c*CCH+k], dr); dd = fmaf(pdl[k], wd[c*CCH+k], dd); }
  dr = fmaxf(dr,0.f); dd = fmaxf(dd,0.f);
  float car = 1.f/(1.f+expf(-dr));
  float cad = 1.f/(1.f+expf(-dd));
  float tv = car+cad;
  red[c]=tv; __syncthreads();
  for(int st=128;st>0;st>>=1){ if(c<st) red[c]=fmaxf(red[c],red[c+st]); __syncthreads(); }
  float mx = red[0]; __syncthreads();
  float e = expf(tv-mx);
  red[c]=e; __syncthreads();
  for(int st=128;st>0;st>>=1){ if(c<st) red[c]+=red[c+st]; __syncthreads(); }
  float co = e/red[0];
  fws[F_SR+n*CCH+c] = co+car;
  fws[F_SD+n*CCH+c] = co+cad;
}

// ============ K3: weight prep ============
__global__ __launch_bounds__(256) void k_wprep(const float* __restrict__ qw, const float* __restrict__ kw,
                                               const float* __restrict__ vw, const float* __restrict__ fws,
                                               bf16* __restrict__ wqs, bf16* __restrict__ wks, bf16* __restrict__ vwb){
  int b = blockIdx.x, t = threadIdx.x;
  if(b<16){
    const float* sr = fws + F_SR + b*CCH;
    const float* sd = fws + F_SD + b*CCH;
    for(int idx=t; idx<128*256; idx+=256){
      int c = idx & 255;
      wqs[b*32768+idx] = f2bf(qw[idx]*sr[c]);
      wks[b*32768+idx] = f2bf(kw[idx]*sd[c]);
    }
  } else {
    for(int idx=t; idx<256*256; idx+=256) vwb[idx] = f2bf(vw[idx]);
  }
}

// ============ K4: MFMA projection GEMM — 64s x 128o tiles ============
__global__ __launch_bounds__(256) void k_gemm(const bf16* __restrict__ xT, const bf16* __restrict__ xdT,
                                              const bf16* __restrict__ xfT,
                                              const bf16* __restrict__ wqs, const bf16* __restrict__ wks,
                                              const bf16* __restrict__ vwb,
                                              float* __restrict__ fws, bf16* __restrict__ proj){
  __shared__ __align__(16) char sm[50176];
  int bid = blockIdx.x;
  int sw = (bid & 7)*392 + (bid >> 3);
  int p = sw & 3;
  int rest = sw >> 2;
  int s_t = rest % 49;
  int n   = rest / 49;
  int s0g = s_t*64;

  const bf16* Ag = (p==0 ? xT : (p==1 ? xdT : xfT)) + (size_t)n*SSP*CCH;
  const bf16* Wg = (p==0) ? (wqs + (size_t)n*32768)
                 : (p==1) ? (wks + (size_t)n*32768)
                          : (vwb + (size_t)(p-2)*128*256);

  int tid = threadIdx.x;
  int w = tid>>6, lane = tid&63;
  int l15 = lane & 15, l4 = lane >> 4;

  float* sst = (float*)(sm + 49152);
  sst[tid]=0.f;

  f32x4 acc[2][4];
  #pragma unroll
  for(int f=0;f<2;f++)
    #pragma unroll
    for(int e=0;e<4;e++) acc[f][e]=(f32x4){0,0,0,0};

  auto stage = [&](int b, int kk){
    #pragma unroll
    for(int j=0;j<2;j++){
      int rowstart = w*16 + j*8;
      int row = rowstart + (lane>>3);
      int ch  = (lane&7) ^ (row&7);
      gl16(Ag + (size_t)(s0g + row)*CCH + kk*64 + ch*8, sm + (b?8192:0) + rowstart*128);
    }
    #pragma unroll
    for(int j=0;j<4;j++){
      int rowstart = w*32 + j*8;
      int row = rowstart + (lane>>3);
      int ch  = (lane&7) ^ (row&7);
      gl16(Wg + (size_t)row*CCH + kk*64 + ch*8, sm + 16384 + (b?16384:0) + rowstart*128);
    }
  };

  stage(0,0);
  __syncthreads();
  int cur=0;
  int sl0 = (w&1)*32, ol0 = (w>>1)*64;
  for(int kk=0;kk<4;kk++){
    if(kk<3) stage(cur^1, kk+1);
    const short* Ab = (const short*)(sm + (cur?8192:0));
    const short* Bb = (const short*)(sm + 16384 + (cur?16384:0));
    #pragma unroll
    for(int kh=0;kh<2;kh++){
      bf16x8 a[2], b[4];
      #pragma unroll
      for(int f=0;f<2;f++){
        int sr = sl0 + f*16 + l15;
        int chv = (kh*4 + l4) ^ (sr&7);
        a[f] = *(const bf16x8*)(Ab + sr*64 + chv*8);
      }
      #pragma unroll
      for(int e=0;e<4;e++){
        int orw = ol0 + e*16 + l15;
        int chv = (kh*4 + l4) ^ (orw&7);
        b[e] = *(const bf16x8*)(Bb + orw*64 + chv*8);
      }
      #pragma unroll
      for(int f=0;f<2;f++)
        #pragma unroll
        for(int e=0;e<4;e++)
          acc[f][e] = __builtin_amdgcn_mfma_f32_16x16x32_bf16(a[f], b[e], acc[f][e], 0,0,0);
    }
    __syncthreads();
    cur ^= 1;
  }

  #pragma unroll
  for(int e=0;e<4;e++){
    float s1=0.f, s2=0.f;
    #pragma unroll
    for(int f=0;f<2;f++)
      #pragma unroll
      for(int r=0;r<4;r++){ float v=acc[f][e][r]; s1+=v; s2+=v*v; }
    s1 += __shfl_xor(s1,16); s2 += __shfl_xor(s2,16);
    s1 += __shfl_xor(s1,32); s2 += __shfl_xor(s2,32);
    if(l4==0){
      int ol = ol0 + e*16 + l15;
      atomicAdd(&sst[ol], s1);
      atomicAdd(&sst[128+ol], s2);
    }
  }
  #pragma unroll
  for(int f=0;f<2;f++)
    #pragma unroll
    for(int e=0;e<4;e++){
      int sbase = s0g + (w&1)*32 + f*16 + l4*4;
      int o = p*128 + ol0 + e*16 + l15;
      short4 pk;
      pk.x = f2s(acc[f][e][0]); pk.y = f2s(acc[f][e][1]);
      pk.z = f2s(acc[f][e][2]); pk.w = f2s(acc[f][e][3]);
      *reinterpret_cast<short4*>(proj + ((size_t)n*OCT + o)*SSP + sbase) = pk;
    }
  __syncthreads();
  if(tid<128){
    int og = p*128 + tid;
    atomicAdd(&fws[F_PSUM+og], sst[tid]);
    atomicAdd(&fws[F_PSQ+og],  sst[128+tid]);
  }
}

// ============ K5: finalize proj BN ============
__global__ void k_finproj(const float* qg,const float* qb,const float* kg,const float* kb,
                          const float* vg,const float* vb, float* fws){
  int o = threadIdx.x;
  float m = fws[F_PSUM+o]*(1.0f/CNT_PROJ);
  float var = fws[F_PSQ+o]*(1.0f/CNT_PROJ) - m*m;
  float g,b;
  if(o<128){ g=qg[o]; b=qb[o]; }
  else if(o<256){ g=kg[o-128]; b=kb[o-128]; }
  else { g=vg[o-256]; b=vb[o-256]; }
  float a = g*rsqrtf(var+EPSV);
  fws[F_PA+o]=a; fws[F_PB+o]=b-m*a;
}

// ============ K6: sim-BN stats — 7 w per block, band-pruned tiles ============
__global__ __launch_bounds__(256) void k_simstat(const bf16* __restrict__ proj,
                                                 const short* __restrict__ tb,
                                                 float* __restrict__ fws){
  __shared__ __align__(16) short smS[2*SB_TOT];
  __shared__ float redW[4][4];
  __shared__ float red2[2];
  int wq = blockIdx.x, n = blockIdx.y, g = blockIdx.z;
  int t = threadIdx.x;
  int W = t>>6, lane = t&63;
  int l15 = lane&15, l4 = lane>>4;
  const short* rqB = tb + T_RQ;
  const short* rkB = tb + T_RK;
  const bf16x8 z8 = {};

  for(int i=t; i<SB_ZI4; i+=256) ((int4*)smS)[i] = (int4){0,0,0,0};

  int isLoader = (t<224);
  int rid = t/7, ch = t - rid*7;
  int isK = rid>=16, c = rid&15;
  int o = (isK?128:0) + g*GPH + c;
  float pa=0.f, pb=0.f;
  const bf16* gsrc = proj + ((size_t)n*OCT+o)*SSP + ch*8;
  if(isLoader){ pa = fws[F_PA+o]; pb = fws[F_PB+o]; }
  int w0 = wq*7;

  auto stageWrite = [&](short* buf, bf16x8 vv){
    bf16x8 rv;
    #pragma unroll
    for(int e=0;e<8;e++) rv[e] = f2s(pa*s2f(vv[e])+pb);
    short* dA = buf + (isK? SB_KA : SB_QA);
    #pragma unroll
    for(int e=0;e<8;e++) dA[(ch*8+e)*STQ + c] = rv[e];
    short* gRow = buf + (isK? SB_KG : SB_QG) + c*STG;
    *(bf16x8*)(gRow + ch*8) = rv;
  };

  bf16x8 ld = z8;
  if(isLoader) ld = *(const bf16x8*)(gsrc + (size_t)w0*HH);
  __syncthreads();
  if(isLoader) stageWrite(smS, ld);
  __syncthreads();

  float sQ=0.f,qQ=0.f,sK=0.f,qK=0.f,pSS=0.f,pS=0.f;
  #pragma unroll 1
  for(int it=0; it<7; it++){
    bf16x8 nx = z8;
    if(it<6 && isLoader) nx = *(const bf16x8*)(gsrc + (size_t)(w0+it+1)*HH);
    const short* buf = smS + (it&1)*SB_TOT;
    const short* qA = buf + SB_QA;
    const short* kA = buf + SB_KA;
    const short* qG = buf + SB_QG;
    const short* kG = buf + SB_KG;

    for(int T=W; T<38; T+=4){
      int tk = (T>=19);
      int t2 = tk ? T-19 : T;
      int ti = t2/5;
      int td = t2 - 4*ti;
      int i0 = ti*16, d0 = td*16;
      const short* aBase = tk ? kA : qA;
      const short* bBase = tk ? rkB : rqB;
      bf16x8 av = (l4<2)? *(const bf16x8*)(aBase + (i0+l15)*STQ + l4*8) : z8;
      bf16x8 bv = (l4<2)? *(const bf16x8*)(bBase + (d0+l15)*24 + l4*8) : z8;
      f32x4 acc = {0.f,0.f,0.f,0.f};
      acc = __builtin_amdgcn_mfma_f32_16x16x32_bf16(av, bv, acc, 0,0,0);
      int d = d0 + l15;
      #pragma unroll
      for(int r=0;r<4;r++){
        int i = i0 + l4*4 + r;
        int dmi = d - i;
        if(dmi>=0 && dmi<56){
          float v = acc[r];
          if(tk){ sK += v; qK += v*v; }
          else  { sQ += v; qQ += v*v; }
        }
      }
    }
    if(W==0){
      bf16x8 a0 = *(const bf16x8*)(qG + l15*STG + l4*8);
      bf16x8 a1 = *(const bf16x8*)(qG + l15*STG + 32 + l4*8);
      f32x4 gq = {0.f,0.f,0.f,0.f};
      gq = __builtin_amdgcn_mfma_f32_16x16x32_bf16(a0, a0, gq, 0,0,0);
      gq = __builtin_amdgcn_mfma_f32_16x16x32_bf16(a1, a1, gq, 0,0,0);
      bf16x8 b0 = *(const bf16x8*)(kG + l15*STG + l4*8);
      bf16x8 b1 = *(const bf16x8*)(kG + l15*STG + 32 + l4*8);
      f32x4 gk = {0.f,0.f,0.f,0.f};
      gk = __builtin_amdgcn_mfma_f32_16x16x32_bf16(b0, b0, gk, 0,0,0);
      gk = __builtin_amdgcn_mfma_f32_16x16x32_bf16(b1, b1, gk, 0,0,0);
      pSS += gq[0]*gk[0]+gq[1]*gk[1]+gq[2]*gk[2]+gq[3]*gk[3];
    } else if(W==1){
      float rsum = 0.f;
      if(lane<32){
        const short* row = (lane<16)? (qG + lane*STG) : (kG + (lane-16)*STG);
        #pragma unroll
        for(int i8=0;i8<7;i8++){
          bf16x8 v8 = *(const bf16x8*)(row + i8*8);
          #pragma unroll
          for(int e=0;e<8;e++) rsum += s2f(v8[e]);
        }
      }
      float kv = __shfl(rsum, (lane+16)&63);
      if(lane<16) pS += rsum*kv;
    }

    if(it<6){
      __syncthreads();
      if(isLoader) stageWrite(smS + ((it+1)&1)*SB_TOT, nx);
      __syncthreads();
    }
  }

  float b4[4] = {sQ,qQ,sK,qK};
  #pragma unroll
  for(int u=0;u<4;u++){
    float v = b4[u];
    #pragma unroll
    for(int msk=1;msk<64;msk<<=1) v += __shfl_xor(v,msk);
    if(lane==0) redW[W][u] = v;
  }
  if(W==0){
    float p = pSS;
    #pragma unroll
    for(int msk=1;msk<64;msk<<=1) p += __shfl_xor(p,msk);
    if(lane==0) red2[1] = p;
  } else if(W==1){
    float p = (lane<16)? pS : 0.f;
    #pragma unroll
    for(int msk=1;msk<16;msk<<=1) p += __shfl_xor(p,msk);
    if(lane==0) red2[0] = p;
  }
  __syncthreads();
  if(t<4){
    float s = redW[0][t]+redW[1][t]+redW[2][t]+redW[3][t];
    int tgt = (t==0)? (F_SSUM+8+g) : (t==1)? (F_SSQ+8+g) : (t==2)? (F_SSUM+16+g) : (F_SSQ+16+g);
    atomicAdd(&fws[tgt], s);
  } else if(t==4){
    atomicAdd(&fws[F_SSUM+g], red2[0]);
  } else if(t==5){
    atomicAdd(&fws[F_SSQ+g], red2[1]);
  }
}

__global__ void k_finsim(const float* sg, const float* sb, float* fws){
  int ch = threadIdx.x; if(ch>=24) return;
  float m = fws[F_SSUM+ch]*(1.0f/CNT_SIM);
  float var = fws[F_SSQ+ch]*(1.0f/CNT_SIM) - m*m;
  float a = sg[ch]*rsqrtf(var+EPSV);
  fws[F_SA+ch]=a; fws[F_SB+ch]=sb[ch]-m*a;
}

// ============ K7: main MFMA attention (1 w/block, band-pruned P2a) ============
__global__ __launch_bounds__(512) void k_att(const bf16* __restrict__ proj,
                                             const short* __restrict__ tb,
                                             float* __restrict__ fws,
                                             bf16* __restrict__ svw, bf16* __restrict__ svew){
  __shared__ __align__(16) char sm[SMSZ];
  int g = blockIdx.x, w = blockIdx.y, n = blockIdx.z;
  int tid = threadIdx.x;
  int W = tid >> 6, lane = tid & 63;
  int l15 = lane & 15, l4 = lane >> 4;
  short* qA = (short*)(sm + OFF_QA);
  short* kA = (short*)(sm + OFF_KA);
  short* qrT = (short*)(sm + OFF_QR);
  short* krT = (short*)(sm + OFF_KR);
  short* vB  = (short*)(sm + OFF_VB);
  float* rfacL = (float*)(sm + OFF_FAC);
  const short* rqB = tb + T_RQ;
  const short* rkB = tb + T_RK;
  const short* rvBg = tb + T_RV;
  const float* PA = fws + F_PA;
  const float* PB = fws + F_PB;
  const bf16x8 z8 = {};

  float aqk = fws[F_SA+g], aqr = fws[F_SA+8+g], akr = fws[F_SA+16+g];
  float bsum = fws[F_SB+g]+fws[F_SB+8+g]+fws[F_SB+16+g];

  if(tid<128) ((float*)(sm+OFF_OST))[tid]=0.f;
  if(tid<448){
    int rid = tid/7, ch = tid - rid*7;
    int o, c, isV=0;
    if(rid<16){ c=rid; o = g*GPH + c; }
    else if(rid<32){ c=rid-16; o = 128 + g*GPH + c; }
    else { c=rid-32; o = 256 + g*GPF + c; isV=1; }
    float pa = PA[o], pb = PB[o];
    const bf16* src = proj + ((size_t)n*OCT + o)*SSP + w*HH + ch*8;
    bf16x8 vv = *(const bf16x8*)src;
    bf16x8 rv;
    #pragma unroll
    for(int e=0;e<8;e++) rv[e] = f2s(pa*s2f(vv[e])+pb);
    if(!isV){
      short* dst = (rid<16)? qA : kA;
      #pragma unroll
      for(int e=0;e<8;e++) dst[(ch*8+e)*STQ + c] = rv[e];
    } else {
      *(bf16x8*)(vB + c*STA + ch*8) = rv;
      if(ch==0){
        *(bf16x8*)(vB + c*STA + 56) = z8;
        *(bf16x8*)(vB + c*STA + 64) = z8;
      }
    }
  } else {
    int z = tid-448;
    if(z<48){
      short* arr = (z<24)? qA : kA;
      int zz = (z<24)? z : z-24;
      *(int4*)((char*)arr + 56*STQ*2 + zz*16) = (int4){0,0,0,0};
    }
  }
  __syncthreads();

  // P2a: band-pruned QR/KR tiles (19 each; only tiles intersecting 0<=d-i<56)
  for(int T=W; T<38; T+=8){
    int isK = (T>=19);
    int t2 = isK ? T-19 : T;
    int ti = t2/5;
    int td = t2 - 4*ti;
    int i0 = ti*16, d0 = td*16;
    const short* aBase = isK ? kA : qA;
    const short* bBase = isK ? rkB : rqB;
    bf16x8 av = (l4<2)? *(const bf16x8*)(aBase + (i0+l15)*STQ + l4*8) : z8;
    bf16x8 bv = (l4<2)? *(const bf16x8*)(bBase + (d0+l15)*24 + l4*8) : z8;
    f32x4 acc = {0.f,0.f,0.f,0.f};
    acc = __builtin_amdgcn_mfma_f32_16x16x32_bf16(av, bv, acc, 0,0,0);
    short* dst = isK ? krT : qrT;
    int d = d0 + l15;
    int ib = i0 + l4*4;
    if(ib < 53){
      unsigned* wp = (unsigned*)(dst + d*SQT + ib);
      wp[0] = pk2(acc[0], acc[1]);
      wp[1] = pk2(acc[2], acc[3]);
    }
  }
  __syncthreads();

  float e8[8];
  #pragma unroll
  for(int tt=0; tt<2; tt++){
    int T = W + 8*tt;
    int ti = T>>2, tj = T&3;
    int i0 = ti*16, j0 = tj*16;
    bf16x8 av = (l4<2)? *(const bf16x8*)(qA + (i0+l15)*STQ + l4*8) : z8;
    bf16x8 bv = (l4<2)? *(const bf16x8*)(kA + (j0+l15)*STQ + l4*8) : z8;
    f32x4 acc = {0.f,0.f,0.f,0.f};
    acc = __builtin_amdgcn_mfma_f32_16x16x32_bf16(av, bv, acc, 0,0,0);
    int j = j0 + l15;
    int jv = (j < HH);
    #pragma unroll
    for(int r=0;r<4;r++){
      int i = i0 + l4*4 + r;
      float vqr = s2f(qrT[(i-j+55)*SQT + i]);
      float vkr = s2f(krT[(j-i+55)*SQT + j]);
      float v = aqk*acc[r] + aqr*vqr + akr*vkr + bsum;
      e8[tt*4+r] = jv ? __expf(v) : 0.f;
    }
  }
  __syncthreads();

  for(int idx=tid; idx<ZERO_I4; idx+=512) ((int4*)sm)[idx] = (int4){0,0,0,0};
  __syncthreads();

  short* simA = (short*)(sm + OFF_SIMA);
  short* simSh = (short*)(sm + OFF_SIMSH);
  #pragma unroll
  for(int tt=0; tt<2; tt++){
    int T = W + 8*tt;
    int ti = T>>2, tj = T&3;
    int j = tj*16 + l15;
    #pragma unroll
    for(int r=0;r<4;r++){
      int i = ti*16 + l4*4 + r;
      if(i<HH && j<HH){
        short pv = f2s(e8[tt*4+r]);
        simA[i*STA + j] = pv;
        simSh[i*STSH + (i+55-j)] = pv;
      }
    }
  }
  __syncthreads();

  if(W>=4){
    int i0 = (W-4)*16;
    const short one_s = 0x3F80;
    bf16x8 onesv = {one_s,one_s,one_s,one_s,one_s,one_s,one_s,one_s};
    bf16x8 bv = (l15==0)? onesv : z8;
    f32x4 acc = {0.f,0.f,0.f,0.f};
    #pragma unroll
    for(int ks=0; ks<2; ks++){
      bf16x8 av = *(const bf16x8*)(simA + (i0+l15)*STA + ks*32 + l4*8);
      acc = __builtin_amdgcn_mfma_f32_16x16x32_bf16(av, bv, acc, 0,0,0);
    }
    if(l15==0){
      #pragma unroll
      for(int r=0;r<4;r++){
        int i = i0 + l4*4 + r;
        if(i<HH) rfacL[i] = 1.0f/acc[r];
      }
    }
  }

  f32x4 accJ[2];
  #pragma unroll
  for(int jt=0; jt<2; jt++){
    int T = W + 8*jt;
    int isE = (T>=8);
    int tt = T&7;
    int ti = tt>>1, tc = tt&1;
    int i0 = ti*16, c0 = tc*16;
    f32x4 acc = {0.f,0.f,0.f,0.f};
    if(!isE){
      #pragma unroll
      for(int ks=0; ks<2; ks++){
        int j0 = ks*32;
        bf16x8 av = *(const bf16x8*)(simA + (i0+l15)*STA + j0 + l4*8);
        bf16x8 bv = *(const bf16x8*)(vB + (c0+l15)*STA + j0 + l4*8);
        acc = __builtin_amdgcn_mfma_f32_16x16x32_bf16(av, bv, acc, 0,0,0);
      }
    } else {
      #pragma unroll
      for(int ks=0; ks<4; ks++){
        int d0 = ks*32;
        bf16x8 av = *(const bf16x8*)(simSh + (i0+l15)*STSH + d0 + l4*8);
        bf16x8 bv = *(const bf16x8*)(rvBg + (c0+l15)*128 + d0 + l4*8);
        acc = __builtin_amdgcn_mfma_f32_16x16x32_bf16(av, bv, acc, 0,0,0);
      }
    }
    accJ[jt] = acc;
  }
  __syncthreads();

  float* ostS = (float*)(sm + OFF_OST);
  float* ostQ = ostS + 64;
  #pragma unroll
  for(int jt=0; jt<2; jt++){
    int T = W + 8*jt;
    int isE = (T>=8);
    int tt = T&7;
    int ti = tt>>1, tc = tt&1;
    int i0 = ti*16, c0 = tc*16;
    f32x4 acc = accJ[jt];
    int c = c0 + l15;
    int ib = i0 + l4*4;
    float s1=0.f, s2=0.f;
    if(ib+3 < HH){
      float4 rf = *(const float4*)(rfacL + ib);
      acc[0]*=rf.x; acc[1]*=rf.y; acc[2]*=rf.z; acc[3]*=rf.w;
      size_t gb = ((((size_t)n*WW + w)*GG + g)*GPF + c)*HH;
      bf16* dst = isE ? svew : svw;
      short4 pk;
      pk.x = f2s(acc[0]); pk.y = f2s(acc[1]); pk.z = f2s(acc[2]); pk.w = f2s(acc[3]);
      *reinterpret_cast<short4*>(dst + gb + ib) = pk;
      #pragma unroll
      for(int r=0;r<4;r++){ s1 += acc[r]; s2 += acc[r]*acc[r]; }
    }
    int u = 2*c + (isE?1:0);
    atomicAdd(&ostS[u], s1);
    atomicAdd(&ostQ[u], s2);
  }
  __syncthreads();
  if(tid<64){
    atomicAdd(&fws[F_OSUM + g*64 + tid], ostS[tid]);
    atomicAdd(&fws[F_OSQ  + g*64 + tid], ostQ[tid]);
  }
}

__global__ void k_finout(const float* og, const float* ob, float* fws){
  int o = threadIdx.x;
  float m = fws[F_OSUM+o]*(1.0f/CNT_PROJ);
  float var = fws[F_OSQ+o]*(1.0f/CNT_PROJ) - m*m;
  float a = og[o]*rsqrtf(var+EPSV);
  fws[F_OA+o]=a; fws[F_OB+o]=ob[o]-m*a;
}

__global__ __launch_bounds__(256) void k_out(const bf16* __restrict__ svw, const bf16* __restrict__ svew,
                                             const float* __restrict__ fws, float* __restrict__ out){
  int oc = blockIdx.x, n = blockIdx.y;
  int g = oc>>5, c = oc&31;
  __shared__ float s1l[WW][57], s2l[WW][57];
  int t=threadIdx.x;
  for(int idx=t; idx<392; idx+=256){
    int w = idx/7, hc = idx-w*7;
    size_t base = (((size_t)(n*WW+w)*GG+g)*GPF+c)*HH + hc*8;
    bf16x8 v1 = *(const bf16x8*)(svw+base);
    bf16x8 v2 = *(const bf16x8*)(svew+base);
    #pragma unroll
    for(int e=0;e<8;e++){
      s1l[w][hc*8+e] = s2f(v1[e]);
      s2l[w][hc*8+e] = s2f(v2[e]);
    }
  }
  int ch0 = g*64+2*c;
  float a1=fws[F_OA+ch0], b1=fws[F_OB+ch0], a2=fws[F_OA+ch0+1], b2=fws[F_OB+ch0+1];
  __syncthreads();
  size_t obase = (size_t)(n*CCH+oc)*SSP;
  for(int idx=t; idx<784; idx+=256){
    int h = idx/14, w4 = (idx-h*14)*4;
    float4 o4;
    o4.x = a1*s1l[w4+0][h]+b1 + a2*s2l[w4+0][h]+b2;
    o4.y = a1*s1l[w4+1][h]+b1 + a2*s2l[w4+1][h]+b2;
    o4.z = a1*s1l[w4+2][h]+b1 + a2*s2l[w4+2][h]+b2;
    o4.w = a1*s1l[w4+3][h]+b1 + a2*s2l[w4+3][h]+b2;
    *reinterpret_cast<float4*>(out + obase + (size_t)h*WW + w4) = o4;
  }
}

extern "C" void kernel_launch(void* const* d_in, const int* in_sizes, int n_in,
                              void* d_out, int out_size, void* d_ws, size_t ws_size,
                              hipStream_t stream) {
  const float* x    = (const float*)d_in[0];
  const float* xd   = (const float*)d_in[1];
  const float* carw = (const float*)d_in[2];
  const float* carb = (const float*)d_in[3];
  const float* cadw = (const float*)d_in[4];
  const float* cadb = (const float*)d_in[5];
  const float* qw   = (const float*)d_in[6];
  const float* kw   = (const float*)d_in[7];
  const float* vw   = (const float*)d_in[8];
  const float* bnqg = (const float*)d_in[9];
  const float* bnqb = (const float*)d_in[10];
  const float* bnkg = (const float*)d_in[11];
  const float* bnkb = (const float*)d_in[12];
  const float* bnvg = (const float*)d_in[13];
  const float* bnvb = (const float*)d_in[14];
  const float* bnsg = (const float*)d_in[15];
  const float* bnsb = (const float*)d_in[16];
  const float* bnog = (const float*)d_in[17];
  const float* bnob = (const float*)d_in[18];
  const float* rel  = (const float*)d_in[19];
  float* out = (float*)d_out;

  char* ws = (char*)d_ws;
  const size_t PROJ_BYTES = (size_t)NN*OCT*SSP*sizeof(bf16);
  const size_t XT_BYTES   = (size_t)NN*SSP*CCH*sizeof(bf16);
  const size_t WQS_BYTES  = (size_t)NN*128*256*sizeof(bf16);
  const size_t VWB_BYTES  = (size_t)256*256*sizeof(bf16);
  const size_t FWS_BYTES  = (size_t)F_TOT*sizeof(float);
  const size_t TB_BYTES   = (size_t)((T_TOT+7)/8*8)*sizeof(short);

  size_t off = 0;
  bf16* proj = (bf16*)(ws + off); off += PROJ_BYTES;
  bf16* xT   = (bf16*)(ws + off); size_t off_xT = off; off += XT_BYTES;
  bf16* xdT  = (bf16*)(ws + off); size_t off_xdT = off; off += XT_BYTES;
  bf16* xfT  = (bf16*)(ws + off); off += XT_BYTES;
  bf16* wqs  = (bf16*)(ws + off); off += WQS_BYTES;
  bf16* wks  = (bf16*)(ws + off); off += WQS_BYTES;
  bf16* vwb  = (bf16*)(ws + off); off += VWB_BYTES;
  float* fws = (float*)(ws + off); off += FWS_BYTES;
  short* tb  = (short*)(ws + off); off += TB_BYTES;
  if (ws_size < off) return;
  bf16* svw  = (bf16*)(ws + off_xT);
  bf16* svew = (bf16*)(ws + off_xdT);

  hipMemsetAsync(fws, 0, (size_t)F_ACC_END*sizeof(float), stream);
  k_prep<<<dim3(98,NN), 256, 0, stream>>>(x, xd, rel, fws, tb, xT, xdT, xfT);
  k_chanatt<<<NN, 256, 0, stream>>>(carw, carb, cadw, cadb, fws);
  k_wprep<<<17, 256, 0, stream>>>(qw, kw, vw, fws, wqs, wks, vwb);
  k_gemm<<<dim3(3136), 256, 0, stream>>>(xT, xdT, xfT, wqs, wks, vwb, fws, proj);
  k_finproj<<<1, 512, 0, stream>>>(bnqg,bnqb,bnkg,bnkb,bnvg,bnvb, fws);
  k_simstat<<<dim3(8,NN,GG), 256, 0, stream>>>(proj, tb, fws);
  k_finsim<<<1, 32, 0, stream>>>(bnsg, bnsb, fws);
  k_att<<<dim3(GG,WW,NN), 512, 0, stream>>>(proj, tb, fws, svw, svew);
  k_finout<<<1, 512, 0, stream>>>(bnog, bnob, fws);
  k_out<<<dim3(CCH,NN), 256, 0, stream>>>(svw, svew, fws, out);
}

// Round 17
// 408.795 us; speedup vs baseline: 5.6208x; 1.0129x over previous
//
#include <hip/hip_runtime.h>
#include <hip/hip_bf16.h>
#include <math.h>

typedef __hip_bfloat16 bf16;
typedef __attribute__((ext_vector_type(8))) short bf16x8;
typedef __attribute__((ext_vector_type(4))) float f32x4;

#define NN 16
#define CCH 256
#define HH 56
#define WW 56
#define SSP 3136
#define GG 8
#define GPH 16
#define GPF 32
#define OCT 512
#define RL 111
#define EPSV 1e-5f
#define CNT_PROJ 50176.0f
#define CNT_SIM  2809856.0f

__device__ __forceinline__ float bf2f(bf16 v){ return __bfloat162float(v); }
__device__ __forceinline__ bf16 f2bf(float v){ return __float2bfloat16(v); }
__device__ __forceinline__ short f2s(float f){ bf16 h = __float2bfloat16(f); return __builtin_bit_cast(short, h); }
__device__ __forceinline__ float s2f(short s){ bf16 h = __builtin_bit_cast(bf16, s); return __bfloat162float(h); }
__device__ __forceinline__ unsigned pk2(float a, float b){
  return (unsigned)(unsigned short)f2s(a) | ((unsigned)(unsigned short)f2s(b)<<16);
}

__device__ __forceinline__ void gl16(const void* g, void* l){
  __builtin_amdgcn_global_load_lds((const __attribute__((address_space(1))) void*)g,
                                   (__attribute__((address_space(3))) void*)l, 16, 0, 0);
}

// ---- f32 workspace region layout (float indices) ----
#define F_PR 0
#define F_PD 4096
#define F_SR 8192
#define F_SD 12288
#define F_PSUM 16384
#define F_PSQ  16896
#define F_PA   17408
#define F_PB   17920
#define F_SSUM 18432
#define F_SSQ  18464
#define F_SA   18496
#define F_SB   18528
#define F_OSUM 18560
#define F_OSQ  19072
#define F_OA   19584
#define F_OB   20096
#define F_ACC_END 20608
#define F_TOT  20608
// bf16 table region (shorts)
#define T_RQ 0        // [112][24]
#define T_RK 2688     // [112][24]
#define T_RV 5376     // [32][128]
#define T_TOT 9472

// k_att LDS layout (bytes)
#define STQ 24
#define SQT 58
#define STA 72
#define STSH 136
#define STG 72
#define OFF_QA   0
#define OFF_KA   3072
#define OFF_QR   6144
#define OFF_KR   19136
#define OFF_VB   32128
#define OFF_FAC  36736
#define OFF_OST  36992
#define SMSZ     37504
#define OFF_SIMA 0
#define OFF_SIMSH 9216
#define ZSH_I4   1088      // simSh bytes (17408) / 16

// k_simstat LDS (shorts per buffer)
#define SB_QA 0
#define SB_KA 1536
#define SB_QG 3072
#define SB_KG 4224
#define SB_TOT 5376
#define SB_ZI4 1344

// ============ K1: prep (+ tables in block (0,0)) ============
__global__ __launch_bounds__(256) void k_prep(const float* __restrict__ x, const float* __restrict__ xd,
                                              const float* __restrict__ rel,
                                              float* __restrict__ fws, short* __restrict__ tb,
                                              bf16* __restrict__ xT, bf16* __restrict__ xdT, bf16* __restrict__ xfT){
  __shared__ __align__(16) short tx[32*264];
  __shared__ __align__(16) short td[32*264];
  __shared__ __align__(16) short tf[32*264];
  int s0 = blockIdx.x*32, n = blockIdx.y;
  int t = threadIdx.x;
  int si = t & 31, cg = t >> 5;
  for(int cc=0; cc<CCH; cc+=8){
    int c = cc + cg;
    size_t gi = ((size_t)n*CCH + c)*SSP + s0 + si;
    float vx = x[gi], vd = xd[gi];
    tx[si*264+c] = f2s(vx);
    td[si*264+c] = f2s(vd);
    tf[si*264+c] = f2s(vx*vd);
  }
  __syncthreads();
  {
    float s1=0.f, s2=0.f;
    for(int sr=0; sr<32; sr++){ s1 += s2f(tx[sr*264+t]); s2 += s2f(td[sr*264+t]); }
    atomicAdd(&fws[F_PR+n*CCH+t], s1);
    atomicAdd(&fws[F_PD+n*CCH+t], s2);
  }
  size_t rbase = (size_t)n*SSP;
  for(int idx=t; idx<32*32; idx+=256){
    int sr2 = idx>>5, ch = idx&31;
    int sp = s0 + sr2;
    int s2 = (sp%WW)*HH + sp/WW;
    float4 v1 = *(const float4*)(tx + sr2*264 + ch*8);
    float4 v2 = *(const float4*)(td + sr2*264 + ch*8);
    float4 v3 = *(const float4*)(tf + sr2*264 + ch*8);
    *reinterpret_cast<float4*>(xT  + (rbase + s2)*CCH + ch*8) = v1;
    *reinterpret_cast<float4*>(xdT + (rbase + s2)*CCH + ch*8) = v2;
    *reinterpret_cast<float4*>(xfT + (rbase + s2)*CCH + ch*8) = v3;
  }
  if(blockIdx.x==0 && blockIdx.y==0){
    for(int idx=t; idx<112*24; idx+=256){
      int d = idx/24, c = idx - d*24;
      short vq=0, vk=0;
      if(c<16 && d<RL){ vq = f2s(rel[c*RL+d]); vk = f2s(rel[(16+c)*RL+d]); }
      tb[T_RQ+idx]=vq; tb[T_RK+idx]=vk;
    }
    for(int idx=t; idx<32*128; idx+=256){
      int c = idx>>7, d = idx&127;
      short v=0;
      if(d<RL) v = f2s(rel[(32+c)*RL+d]);
      tb[T_RV+idx]=v;
    }
  }
}

// ============ K2: channel attention scales ============
__global__ __launch_bounds__(256) void k_chanatt(const float* __restrict__ wr, const float* __restrict__ br,
                                                 const float* __restrict__ wd, const float* __restrict__ bd,
                                                 float* __restrict__ fws){
  int c = threadIdx.x, n = blockIdx.x;
  __shared__ float red[256];
  __shared__ float prl[256], pdl[256];
  prl[c]=fws[F_PR+n*CCH+c]*(1.f/SSP); pdl[c]=fws[F_PD+n*CCH+c]*(1.f/SSP);
  __syncthreads();
  float dr=br[c], dd=bd[c];
  for(int k=0;k<CCH;k++){ dr = fmaf(prl[k], wr[c*CCH+k], dr); dd = fmaf(pdl[k], wd[c*CCH+k], dd); }
  dr = fmaxf(dr,0.f); dd = fmaxf(dd,0.f);
  float car = 1.f/(1.f+expf(-dr));
  float cad = 1.f/(1.f+expf(-dd));
  float tv = car+cad;
  red[c]=tv; __syncthreads();
  for(int st=128;st>0;st>>=1){ if(c<st) red[c]=fmaxf(red[c],red[c+st]); __syncthreads(); }
  float mx = red[0]; __syncthreads();
  float e = expf(tv-mx);
  red[c]=e; __syncthreads();
  for(int st=128;st>0;st>>=1){ if(c<st) red[c]+=red[c+st]; __syncthreads(); }
  float co = e/red[0];
  fws[F_SR+n*CCH+c] = co+car;
  fws[F_SD+n*CCH+c] = co+cad;
}

// ============ K3: weight prep ============
__global__ __launch_bounds__(256) void k_wprep(const float* __restrict__ qw, const float* __restrict__ kw,
                                               const float* __restrict__ vw, const float* __restrict__ fws,
                                               bf16* __restrict__ wqs, bf16* __restrict__ wks, bf16* __restrict__ vwb){
  int b = blockIdx.x, t = threadIdx.x;
  if(b<16){
    const float* sr = fws + F_SR + b*CCH;
    const float* sd = fws + F_SD + b*CCH;
    for(int idx=t; idx<128*256; idx+=256){
      int c = idx & 255;
      wqs[b*32768+idx] = f2bf(qw[idx]*sr[c]);
      wks[b*32768+idx] = f2bf(kw[idx]*sd[c]);
    }
  } else {
    for(int idx=t; idx<256*256; idx+=256) vwb[idx] = f2bf(vw[idx]);
  }
}

// ============ K4: MFMA projection GEMM — 64s x 128o tiles ============
__global__ __launch_bounds__(256) void k_gemm(const bf16* __restrict__ xT, const bf16* __restrict__ xdT,
                                              const bf16* __restrict__ xfT,
                                              const bf16* __restrict__ wqs, const bf16* __restrict__ wks,
                                              const bf16* __restrict__ vwb,
                                              float* __restrict__ fws, bf16* __restrict__ proj){
  __shared__ __align__(16) char sm[50176];
  int bid = blockIdx.x;
  int sw = (bid & 7)*392 + (bid >> 3);
  int p = sw & 3;
  int rest = sw >> 2;
  int s_t = rest % 49;
  int n   = rest / 49;
  int s0g = s_t*64;

  const bf16* Ag = (p==0 ? xT : (p==1 ? xdT : xfT)) + (size_t)n*SSP*CCH;
  const bf16* Wg = (p==0) ? (wqs + (size_t)n*32768)
                 : (p==1) ? (wks + (size_t)n*32768)
                          : (vwb + (size_t)(p-2)*128*256);

  int tid = threadIdx.x;
  int w = tid>>6, lane = tid&63;
  int l15 = lane & 15, l4 = lane >> 4;

  float* sst = (float*)(sm + 49152);
  sst[tid]=0.f;

  f32x4 acc[2][4];
  #pragma unroll
  for(int f=0;f<2;f++)
    #pragma unroll
    for(int e=0;e<4;e++) acc[f][e]=(f32x4){0,0,0,0};

  auto stage = [&](int b, int kk){
    #pragma unroll
    for(int j=0;j<2;j++){
      int rowstart = w*16 + j*8;
      int row = rowstart + (lane>>3);
      int ch  = (lane&7) ^ (row&7);
      gl16(Ag + (size_t)(s0g + row)*CCH + kk*64 + ch*8, sm + (b?8192:0) + rowstart*128);
    }
    #pragma unroll
    for(int j=0;j<4;j++){
      int rowstart = w*32 + j*8;
      int row = rowstart + (lane>>3);
      int ch  = (lane&7) ^ (row&7);
      gl16(Wg + (size_t)row*CCH + kk*64 + ch*8, sm + 16384 + (b?16384:0) + rowstart*128);
    }
  };

  stage(0,0);
  __syncthreads();
  int cur=0;
  int sl0 = (w&1)*32, ol0 = (w>>1)*64;
  for(int kk=0;kk<4;kk++){
    if(kk<3) stage(cur^1, kk+1);
    const short* Ab = (const short*)(sm + (cur?8192:0));
    const short* Bb = (const short*)(sm + 16384 + (cur?16384:0));
    #pragma unroll
    for(int kh=0;kh<2;kh++){
      bf16x8 a[2], b[4];
      #pragma unroll
      for(int f=0;f<2;f++){
        int sr = sl0 + f*16 + l15;
        int chv = (kh*4 + l4) ^ (sr&7);
        a[f] = *(const bf16x8*)(Ab + sr*64 + chv*8);
      }
      #pragma unroll
      for(int e=0;e<4;e++){
        int orw = ol0 + e*16 + l15;
        int chv = (kh*4 + l4) ^ (orw&7);
        b[e] = *(const bf16x8*)(Bb + orw*64 + chv*8);
      }
      #pragma unroll
      for(int f=0;f<2;f++)
        #pragma unroll
        for(int e=0;e<4;e++)
          acc[f][e] = __builtin_amdgcn_mfma_f32_16x16x32_bf16(a[f], b[e], acc[f][e], 0,0,0);
    }
    __syncthreads();
    cur ^= 1;
  }

  #pragma unroll
  for(int e=0;e<4;e++){
    float s1=0.f, s2=0.f;
    #pragma unroll
    for(int f=0;f<2;f++)
      #pragma unroll
      for(int r=0;r<4;r++){ float v=acc[f][e][r]; s1+=v; s2+=v*v; }
    s1 += __shfl_xor(s1,16); s2 += __shfl_xor(s2,16);
    s1 += __shfl_xor(s1,32); s2 += __shfl_xor(s2,32);
    if(l4==0){
      int ol = ol0 + e*16 + l15;
      atomicAdd(&sst[ol], s1);
      atomicAdd(&sst[128+ol], s2);
    }
  }
  #pragma unroll
  for(int f=0;f<2;f++)
    #pragma unroll
    for(int e=0;e<4;e++){
      int sbase = s0g + (w&1)*32 + f*16 + l4*4;
      int o = p*128 + ol0 + e*16 + l15;
      short4 pk;
      pk.x = f2s(acc[f][e][0]); pk.y = f2s(acc[f][e][1]);
      pk.z = f2s(acc[f][e][2]); pk.w = f2s(acc[f][e][3]);
      *reinterpret_cast<short4*>(proj + ((size_t)n*OCT + o)*SSP + sbase) = pk;
    }
  __syncthreads();
  if(tid<128){
    int og = p*128 + tid;
    atomicAdd(&fws[F_PSUM+og], sst[tid]);
    atomicAdd(&fws[F_PSQ+og],  sst[128+tid]);
  }
}

// ============ K5: finalize proj BN ============
__global__ void k_finproj(const float* qg,const float* qb,const float* kg,const float* kb,
                          const float* vg,const float* vb, float* fws){
  int o = threadIdx.x;
  float m = fws[F_PSUM+o]*(1.0f/CNT_PROJ);
  float var = fws[F_PSQ+o]*(1.0f/CNT_PROJ) - m*m;
  float g,b;
  if(o<128){ g=qg[o]; b=qb[o]; }
  else if(o<256){ g=kg[o-128]; b=kb[o-128]; }
  else { g=vg[o-256]; b=vb[o-256]; }
  float a = g*rsqrtf(var+EPSV);
  fws[F_PA+o]=a; fws[F_PB+o]=b-m*a;
}

// ============ K6: sim-BN stats — 7 w per block, band-pruned tiles ============
__global__ __launch_bounds__(256) void k_simstat(const bf16* __restrict__ proj,
                                                 const short* __restrict__ tb,
                                                 float* __restrict__ fws){
  __shared__ __align__(16) short smS[2*SB_TOT];
  __shared__ float redW[4][4];
  __shared__ float red2[2];
  int wq = blockIdx.x, n = blockIdx.y, g = blockIdx.z;
  int t = threadIdx.x;
  int W = t>>6, lane = t&63;
  int l15 = lane&15, l4 = lane>>4;
  const short* rqB = tb + T_RQ;
  const short* rkB = tb + T_RK;
  const bf16x8 z8 = {};

  for(int i=t; i<SB_ZI4; i+=256) ((int4*)smS)[i] = (int4){0,0,0,0};

  int isLoader = (t<224);
  int rid = t/7, ch = t - rid*7;
  int isK = rid>=16, c = rid&15;
  int o = (isK?128:0) + g*GPH + c;
  float pa=0.f, pb=0.f;
  const bf16* gsrc = proj + ((size_t)n*OCT+o)*SSP + ch*8;
  if(isLoader){ pa = fws[F_PA+o]; pb = fws[F_PB+o]; }
  int w0 = wq*7;

  auto stageWrite = [&](short* buf, bf16x8 vv){
    bf16x8 rv;
    #pragma unroll
    for(int e=0;e<8;e++) rv[e] = f2s(pa*s2f(vv[e])+pb);
    short* dA = buf + (isK? SB_KA : SB_QA);
    #pragma unroll
    for(int e=0;e<8;e++) dA[(ch*8+e)*STQ + c] = rv[e];
    short* gRow = buf + (isK? SB_KG : SB_QG) + c*STG;
    *(bf16x8*)(gRow + ch*8) = rv;
  };

  bf16x8 ld = z8;
  if(isLoader) ld = *(const bf16x8*)(gsrc + (size_t)w0*HH);
  __syncthreads();
  if(isLoader) stageWrite(smS, ld);
  __syncthreads();

  float sQ=0.f,qQ=0.f,sK=0.f,qK=0.f,pSS=0.f,pS=0.f;
  #pragma unroll 1
  for(int it=0; it<7; it++){
    bf16x8 nx = z8;
    if(it<6 && isLoader) nx = *(const bf16x8*)(gsrc + (size_t)(w0+it+1)*HH);
    const short* buf = smS + (it&1)*SB_TOT;
    const short* qA = buf + SB_QA;
    const short* kA = buf + SB_KA;
    const short* qG = buf + SB_QG;
    const short* kG = buf + SB_KG;

    for(int T=W; T<38; T+=4){
      int tk = (T>=19);
      int t2 = tk ? T-19 : T;
      int ti = t2/5;
      int td = t2 - 4*ti;
      int i0 = ti*16, d0 = td*16;
      const short* aBase = tk ? kA : qA;
      const short* bBase = tk ? rkB : rqB;
      bf16x8 av = (l4<2)? *(const bf16x8*)(aBase + (i0+l15)*STQ + l4*8) : z8;
      bf16x8 bv = (l4<2)? *(const bf16x8*)(bBase + (d0+l15)*24 + l4*8) : z8;
      f32x4 acc = {0.f,0.f,0.f,0.f};
      acc = __builtin_amdgcn_mfma_f32_16x16x32_bf16(av, bv, acc, 0,0,0);
      int d = d0 + l15;
      #pragma unroll
      for(int r=0;r<4;r++){
        int i = i0 + l4*4 + r;
        int dmi = d - i;
        if(dmi>=0 && dmi<56){
          float v = acc[r];
          if(tk){ sK += v; qK += v*v; }
          else  { sQ += v; qQ += v*v; }
        }
      }
    }
    if(W==0){
      bf16x8 a0 = *(const bf16x8*)(qG + l15*STG + l4*8);
      bf16x8 a1 = *(const bf16x8*)(qG + l15*STG + 32 + l4*8);
      f32x4 gq = {0.f,0.f,0.f,0.f};
      gq = __builtin_amdgcn_mfma_f32_16x16x32_bf16(a0, a0, gq, 0,0,0);
      gq = __builtin_amdgcn_mfma_f32_16x16x32_bf16(a1, a1, gq, 0,0,0);
      bf16x8 b0 = *(const bf16x8*)(kG + l15*STG + l4*8);
      bf16x8 b1 = *(const bf16x8*)(kG + l15*STG + 32 + l4*8);
      f32x4 gk = {0.f,0.f,0.f,0.f};
      gk = __builtin_amdgcn_mfma_f32_16x16x32_bf16(b0, b0, gk, 0,0,0);
      gk = __builtin_amdgcn_mfma_f32_16x16x32_bf16(b1, b1, gk, 0,0,0);
      pSS += gq[0]*gk[0]+gq[1]*gk[1]+gq[2]*gk[2]+gq[3]*gk[3];
    } else if(W==1){
      float rsum = 0.f;
      if(lane<32){
        const short* row = (lane<16)? (qG + lane*STG) : (kG + (lane-16)*STG);
        #pragma unroll
        for(int i8=0;i8<7;i8++){
          bf16x8 v8 = *(const bf16x8*)(row + i8*8);
          #pragma unroll
          for(int e=0;e<8;e++) rsum += s2f(v8[e]);
        }
      }
      float kv = __shfl(rsum, (lane+16)&63);
      if(lane<16) pS += rsum*kv;
    }

    if(it<6){
      __syncthreads();
      if(isLoader) stageWrite(smS + ((it+1)&1)*SB_TOT, nx);
      __syncthreads();
    }
  }

  float b4[4] = {sQ,qQ,sK,qK};
  #pragma unroll
  for(int u=0;u<4;u++){
    float v = b4[u];
    #pragma unroll
    for(int msk=1;msk<64;msk<<=1) v += __shfl_xor(v,msk);
    if(lane==0) redW[W][u] = v;
  }
  if(W==0){
    float p = pSS;
    #pragma unroll
    for(int msk=1;msk<64;msk<<=1) p += __shfl_xor(p,msk);
    if(lane==0) red2[1] = p;
  } else if(W==1){
    float p = (lane<16)? pS : 0.f;
    #pragma unroll
    for(int msk=1;msk<16;msk<<=1) p += __shfl_xor(p,msk);
    if(lane==0) red2[0] = p;
  }
  __syncthreads();
  if(t<4){
    float s = redW[0][t]+redW[1][t]+redW[2][t]+redW[3][t];
    int tgt = (t==0)? (F_SSUM+8+g) : (t==1)? (F_SSQ+8+g) : (t==2)? (F_SSUM+16+g) : (F_SSQ+16+g);
    atomicAdd(&fws[tgt], s);
  } else if(t==4){
    atomicAdd(&fws[F_SSUM+g], red2[0]);
  } else if(t==5){
    atomicAdd(&fws[F_SSQ+g], red2[1]);
  }
}

__global__ void k_finsim(const float* sg, const float* sb, float* fws){
  int ch = threadIdx.x; if(ch>=24) return;
  float m = fws[F_SSUM+ch]*(1.0f/CNT_SIM);
  float var = fws[F_SSQ+ch]*(1.0f/CNT_SIM) - m*m;
  float a = sg[ch]*rsqrtf(var+EPSV);
  fws[F_SA+ch]=a; fws[F_SB+ch]=sb[ch]-m*a;
}

// ============ K7: main MFMA attention (band-pruned; SVE ks-pruned; lean zero) ============
__global__ __launch_bounds__(512) void k_att(const bf16* __restrict__ proj,
                                             const short* __restrict__ tb,
                                             float* __restrict__ fws,
                                             bf16* __restrict__ svw, bf16* __restrict__ svew){
  __shared__ __align__(16) char sm[SMSZ];
  int g = blockIdx.x, w = blockIdx.y, n = blockIdx.z;
  int tid = threadIdx.x;
  int W = tid >> 6, lane = tid & 63;
  int l15 = lane & 15, l4 = lane >> 4;
  short* qA = (short*)(sm + OFF_QA);
  short* kA = (short*)(sm + OFF_KA);
  short* qrT = (short*)(sm + OFF_QR);
  short* krT = (short*)(sm + OFF_KR);
  short* vB  = (short*)(sm + OFF_VB);
  float* rfacL = (float*)(sm + OFF_FAC);
  const short* rqB = tb + T_RQ;
  const short* rkB = tb + T_RK;
  const short* rvBg = tb + T_RV;
  const float* PA = fws + F_PA;
  const float* PB = fws + F_PB;
  const bf16x8 z8 = {};

  float aqk = fws[F_SA+g], aqr = fws[F_SA+8+g], akr = fws[F_SA+16+g];
  float bsum = fws[F_SB+g]+fws[F_SB+8+g]+fws[F_SB+16+g];

  if(tid<128) ((float*)(sm+OFF_OST))[tid]=0.f;
  if(tid<448){
    int rid = tid/7, ch = tid - rid*7;
    int o, c, isV=0;
    if(rid<16){ c=rid; o = g*GPH + c; }
    else if(rid<32){ c=rid-16; o = 128 + g*GPH + c; }
    else { c=rid-32; o = 256 + g*GPF + c; isV=1; }
    float pa = PA[o], pb = PB[o];
    const bf16* src = proj + ((size_t)n*OCT + o)*SSP + w*HH + ch*8;
    bf16x8 vv = *(const bf16x8*)src;
    bf16x8 rv;
    #pragma unroll
    for(int e=0;e<8;e++) rv[e] = f2s(pa*s2f(vv[e])+pb);
    if(!isV){
      short* dst = (rid<16)? qA : kA;
      #pragma unroll
      for(int e=0;e<8;e++) dst[(ch*8+e)*STQ + c] = rv[e];
    } else {
      *(bf16x8*)(vB + c*STA + ch*8) = rv;
      if(ch==0){
        *(bf16x8*)(vB + c*STA + 56) = z8;
        *(bf16x8*)(vB + c*STA + 64) = z8;
      }
    }
  } else {
    int z = tid-448;
    if(z<48){
      short* arr = (z<24)? qA : kA;
      int zz = (z<24)? z : z-24;
      *(int4*)((char*)arr + 56*STQ*2 + zz*16) = (int4){0,0,0,0};
    }
  }
  __syncthreads();

  // P2a: band-pruned QR/KR tiles (19 each)
  for(int T=W; T<38; T+=8){
    int isK = (T>=19);
    int t2 = isK ? T-19 : T;
    int ti = t2/5;
    int td = t2 - 4*ti;
    int i0 = ti*16, d0 = td*16;
    const short* aBase = isK ? kA : qA;
    const short* bBase = isK ? rkB : rqB;
    bf16x8 av = (l4<2)? *(const bf16x8*)(aBase + (i0+l15)*STQ + l4*8) : z8;
    bf16x8 bv = (l4<2)? *(const bf16x8*)(bBase + (d0+l15)*24 + l4*8) : z8;
    f32x4 acc = {0.f,0.f,0.f,0.f};
    acc = __builtin_amdgcn_mfma_f32_16x16x32_bf16(av, bv, acc, 0,0,0);
    short* dst = isK ? krT : qrT;
    int d = d0 + l15;
    int ib = i0 + l4*4;
    if(ib < 53){
      unsigned* wp = (unsigned*)(dst + d*SQT + ib);
      wp[0] = pk2(acc[0], acc[1]);
      wp[1] = pk2(acc[2], acc[3]);
    }
  }
  __syncthreads();

  float e8[8];
  #pragma unroll
  for(int tt=0; tt<2; tt++){
    int T = W + 8*tt;
    int ti = T>>2, tj = T&3;
    int i0 = ti*16, j0 = tj*16;
    bf16x8 av = (l4<2)? *(const bf16x8*)(qA + (i0+l15)*STQ + l4*8) : z8;
    bf16x8 bv = (l4<2)? *(const bf16x8*)(kA + (j0+l15)*STQ + l4*8) : z8;
    f32x4 acc = {0.f,0.f,0.f,0.f};
    acc = __builtin_amdgcn_mfma_f32_16x16x32_bf16(av, bv, acc, 0,0,0);
    int j = j0 + l15;
    int jv = (j < HH);
    #pragma unroll
    for(int r=0;r<4;r++){
      int i = i0 + l4*4 + r;
      float vqr = s2f(qrT[(i-j+55)*SQT + i]);
      float vkr = s2f(krT[(j-i+55)*SQT + j]);
      float v = aqk*acc[r] + aqr*vqr + akr*vkr + bsum;
      e8[tt*4+r] = jv ? __expf(v) : 0.f;
    }
  }
  __syncthreads();

  // zero only simSh region (simA zeros come from the unguarded scatter)
  for(int idx=tid; idx<ZSH_I4; idx+=512) ((int4*)(sm+OFF_SIMSH))[idx] = (int4){0,0,0,0};
  __syncthreads();

  short* simA = (short*)(sm + OFF_SIMA);
  short* simSh = (short*)(sm + OFF_SIMSH);
  #pragma unroll
  for(int tt=0; tt<2; tt++){
    int T = W + 8*tt;
    int ti = T>>2, tj = T&3;
    int j = tj*16 + l15;
    #pragma unroll
    for(int r=0;r<4;r++){
      int i = ti*16 + l4*4 + r;
      if(i<HH){
        short pv = f2s(e8[tt*4+r]);
        simA[i*STA + j] = pv;                       // j>=56 writes pv=0 (zero-fill)
        if(j <= i+55) simSh[i*STSH + (i+55-j)] = pv; // j>=56 lands on its own slot, value 0
      }
    }
  }
  __syncthreads();

  if(W>=4){
    int i0 = (W-4)*16;
    const short one_s = 0x3F80;
    bf16x8 onesv = {one_s,one_s,one_s,one_s,one_s,one_s,one_s,one_s};
    bf16x8 bv = (l15==0)? onesv : z8;
    f32x4 acc = {0.f,0.f,0.f,0.f};
    #pragma unroll
    for(int ks=0; ks<2; ks++){
      bf16x8 av = *(const bf16x8*)(simA + (i0+l15)*STA + ks*32 + l4*8);
      acc = __builtin_amdgcn_mfma_f32_16x16x32_bf16(av, bv, acc, 0,0,0);
    }
    if(l15==0){
      #pragma unroll
      for(int r=0;r<4;r++){
        int i = i0 + l4*4 + r;
        if(i<HH) rfacL[i] = 1.0f/acc[r];
      }
    }
  }

  f32x4 accJ[2];
  #pragma unroll
  for(int jt=0; jt<2; jt++){
    int T = W + 8*jt;
    int isE = (T>=8);
    int tt = T&7;
    int ti = tt>>1, tc = tt&1;
    int i0 = ti*16, c0 = tc*16;
    f32x4 acc = {0.f,0.f,0.f,0.f};
    if(!isE){
      #pragma unroll
      for(int ks=0; ks<2; ks++){
        int j0 = ks*32;
        bf16x8 av = *(const bf16x8*)(simA + (i0+l15)*STA + j0 + l4*8);
        bf16x8 bv = *(const bf16x8*)(vB + (c0+l15)*STA + j0 + l4*8);
        acc = __builtin_amdgcn_mfma_f32_16x16x32_bf16(av, bv, acc, 0,0,0);
      }
    } else {
      // SVE ks band-prune: rows [i0,i0+15] have nonzero simSh only at d in [i0, i0+70]
      int ks0 = (i0>=32)? 1 : 0;
      #pragma unroll
      for(int kq=0; kq<3; kq++){
        int d0 = (ks0+kq)*32;
        bf16x8 av = *(const bf16x8*)(simSh + (i0+l15)*STSH + d0 + l4*8);
        bf16x8 bv = *(const bf16x8*)(rvBg + (c0+l15)*128 + d0 + l4*8);
        acc = __builtin_amdgcn_mfma_f32_16x16x32_bf16(av, bv, acc, 0,0,0);
      }
    }
    accJ[jt] = acc;
  }
  __syncthreads();

  float* ostS = (float*)(sm + OFF_OST);
  float* ostQ = ostS + 64;
  #pragma unroll
  for(int jt=0; jt<2; jt++){
    int T = W + 8*jt;
    int isE = (T>=8);
    int tt = T&7;
    int ti = tt>>1, tc = tt&1;
    int i0 = ti*16, c0 = tc*16;
    f32x4 acc = accJ[jt];
    int c = c0 + l15;
    int ib = i0 + l4*4;
    float s1=0.f, s2=0.f;
    if(ib+3 < HH){
      float4 rf = *(const float4*)(rfacL + ib);
      acc[0]*=rf.x; acc[1]*=rf.y; acc[2]*=rf.z; acc[3]*=rf.w;
      size_t gb = ((((size_t)n*WW + w)*GG + g)*GPF + c)*HH;
      bf16* dst = isE ? svew : svw;
      short4 pk;
      pk.x = f2s(acc[0]); pk.y = f2s(acc[1]); pk.z = f2s(acc[2]); pk.w = f2s(acc[3]);
      *reinterpret_cast<short4*>(dst + gb + ib) = pk;
      #pragma unroll
      for(int r=0;r<4;r++){ s1 += acc[r]; s2 += acc[r]*acc[r]; }
    }
    int u = 2*c + (isE?1:0);
    atomicAdd(&ostS[u], s1);
    atomicAdd(&ostQ[u], s2);
  }
  __syncthreads();
  if(tid<64){
    atomicAdd(&fws[F_OSUM + g*64 + tid], ostS[tid]);
    atomicAdd(&fws[F_OSQ  + g*64 + tid], ostQ[tid]);
  }
}

__global__ void k_finout(const float* og, const float* ob, float* fws){
  int o = threadIdx.x;
  float m = fws[F_OSUM+o]*(1.0f/CNT_PROJ);
  float var = fws[F_OSQ+o]*(1.0f/CNT_PROJ) - m*m;
  float a = og[o]*rsqrtf(var+EPSV);
  fws[F_OA+o]=a; fws[F_OB+o]=ob[o]-m*a;
}

__global__ __launch_bounds__(256) void k_out(const bf16* __restrict__ svw, const bf16* __restrict__ svew,
                                             const float* __restrict__ fws, float* __restrict__ out){
  int oc = blockIdx.x, n = blockIdx.y;
  int g = oc>>5, c = oc&31;
  __shared__ float s1l[WW][57], s2l[WW][57];
  int t=threadIdx.x;
  for(int idx=t; idx<392; idx+=256){
    int w = idx/7, hc = idx-w*7;
    size_t base = (((size_t)(n*WW+w)*GG+g)*GPF+c)*HH + hc*8;
    bf16x8 v1 = *(const bf16x8*)(svw+base);
    bf16x8 v2 = *(const bf16x8*)(svew+base);
    #pragma unroll
    for(int e=0;e<8;e++){
      s1l[w][hc*8+e] = s2f(v1[e]);
      s2l[w][hc*8+e] = s2f(v2[e]);
    }
  }
  int ch0 = g*64+2*c;
  float a1=fws[F_OA+ch0], b1=fws[F_OB+ch0], a2=fws[F_OA+ch0+1], b2=fws[F_OB+ch0+1];
  __syncthreads();
  size_t obase = (size_t)(n*CCH+oc)*SSP;
  for(int idx=t; idx<784; idx+=256){
    int h = idx/14, w4 = (idx-h*14)*4;
    float4 o4;
    o4.x = a1*s1l[w4+0][h]+b1 + a2*s2l[w4+0][h]+b2;
    o4.y = a1*s1l[w4+1][h]+b1 + a2*s2l[w4+1][h]+b2;
    o4.z = a1*s1l[w4+2][h]+b1 + a2*s2l[w4+2][h]+b2;
    o4.w = a1*s1l[w4+3][h]+b1 + a2*s2l[w4+3][h]+b2;
    *reinterpret_cast<float4*>(out + obase + (size_t)h*WW + w4) = o4;
  }
}

extern "C" void kernel_launch(void* const* d_in, const int* in_sizes, int n_in,
                              void* d_out, int out_size, void* d_ws, size_t ws_size,
                              hipStream_t stream) {
  const float* x    = (const float*)d_in[0];
  const float* xd   = (const float*)d_in[1];
  const float* carw = (const float*)d_in[2];
  const float* carb = (const float*)d_in[3];
  const float* cadw = (const float*)d_in[4];
  const float* cadb = (const float*)d_in[5];
  const float* qw   = (const float*)d_in[6];
  const float* kw   = (const float*)d_in[7];
  const float* vw   = (const float*)d_in[8];
  const float* bnqg = (const float*)d_in[9];
  const float* bnqb = (const float*)d_in[10];
  const float* bnkg = (const float*)d_in[11];
  const float* bnkb = (const float*)d_in[12];
  const float* bnvg = (const float*)d_in[13];
  const float* bnvb = (const float*)d_in[14];
  const float* bnsg = (const float*)d_in[15];
  const float* bnsb = (const float*)d_in[16];
  const float* bnog = (const float*)d_in[17];
  const float* bnob = (const float*)d_in[18];
  const float* rel  = (const float*)d_in[19];
  float* out = (float*)d_out;

  char* ws = (char*)d_ws;
  const size_t PROJ_BYTES = (size_t)NN*OCT*SSP*sizeof(bf16);
  const size_t XT_BYTES   = (size_t)NN*SSP*CCH*sizeof(bf16);
  const size_t WQS_BYTES  = (size_t)NN*128*256*sizeof(bf16);
  const size_t VWB_BYTES  = (size_t)256*256*sizeof(bf16);
  const size_t FWS_BYTES  = (size_t)F_TOT*sizeof(float);
  const size_t TB_BYTES   = (size_t)((T_TOT+7)/8*8)*sizeof(short);

  size_t off = 0;
  bf16* proj = (bf16*)(ws + off); off += PROJ_BYTES;
  bf16* xT   = (bf16*)(ws + off); size_t off_xT = off; off += XT_BYTES;
  bf16* xdT  = (bf16*)(ws + off); size_t off_xdT = off; off += XT_BYTES;
  bf16* xfT  = (bf16*)(ws + off); off += XT_BYTES;
  bf16* wqs  = (bf16*)(ws + off); off += WQS_BYTES;
  bf16* wks  = (bf16*)(ws + off); off += WQS_BYTES;
  bf16* vwb  = (bf16*)(ws + off); off += VWB_BYTES;
  float* fws = (float*)(ws + off); off += FWS_BYTES;
  short* tb  = (short*)(ws + off); off += TB_BYTES;
  if (ws_size < off) return;
  bf16* svw  = (bf16*)(ws + off_xT);
  bf16* svew = (bf16*)(ws + off_xdT);

  hipMemsetAsync(fws, 0, (size_t)F_ACC_END*sizeof(float), stream);
  k_prep<<<dim3(98,NN), 256, 0, stream>>>(x, xd, rel, fws, tb, xT, xdT, xfT);
  k_chanatt<<<NN, 256, 0, stream>>>(carw, carb, cadw, cadb, fws);
  k_wprep<<<17, 256, 0, stream>>>(qw, kw, vw, fws, wqs, wks, vwb);
  k_gemm<<<dim3(3136), 256, 0, stream>>>(xT, xdT, xfT, wqs, wks, vwb, fws, proj);
  k_finproj<<<1, 512, 0, stream>>>(bnqg,bnqb,bnkg,bnkb,bnvg,bnvb, fws);
  k_simstat<<<dim3(8,NN,GG), 256, 0, stream>>>(proj, tb, fws);
  k_finsim<<<1, 32, 0, stream>>>(bnsg, bnsb, fws);
  k_att<<<dim3(GG,WW,NN), 512, 0, stream>>>(proj, tb, fws, svw, svew);
  k_finout<<<1, 512, 0, stream>>>(bnog, bnob, fws);
  k_out<<<dim3(CCH,NN), 256, 0, stream>>>(svw, svew, fws, out);
}